// Round 3
// baseline (5831.531 us; speedup 1.0000x reference)
//
#include <hip/hip_runtime.h>
#include <math.h>

#define B_TOT 2048
#define SEQ   512
#define DIN   5
#define HID   64
#define G4    256
#define EDIM  32
#define NEMB  64
#define BT    8
#define COMB  96
#define OUTC  (B_TOT*COMB)

__device__ __forceinline__ float fsig(float x){ return 1.0f/(1.0f + __expf(-x)); }
__device__ __forceinline__ float ftanh(float x){
  float xc = fminf(fmaxf(x, -15.f), 15.f);
  float e  = __expf(-2.f*xc);
  return (1.f - e) / (1.f + e);
}

// thread map (1024 threads): p = tid&7 (K-slice), rg = tid>>3 (row pair 2rg,2rg+1)
// act threads: tid<512, abt = tid>>6 (batch), au = tid&63 (unit); wave-uniform abt.

// ===================== CNN stream =====================
__global__ __launch_bounds__(1024)
__attribute__((amdgpu_waves_per_eu(4, 4)))
void cnn_stream_kernel(const float* __restrict__ xg,
                       const float* __restrict__ conv_w, const float* __restrict__ conv_b,
                       const float* __restrict__ bn_g, const float* __restrict__ bn_b,
                       const float* __restrict__ bn_m, const float* __restrict__ bn_v,
                       const float* __restrict__ wih0, const float* __restrict__ whh0,
                       const float* __restrict__ bih0, const float* __restrict__ bhh0,
                       const float* __restrict__ wih1, const float* __restrict__ whh1,
                       const float* __restrict__ bih1, const float* __restrict__ bhh1,
                       float* __restrict__ out)
{
  __shared__ __align__(16) float zbuf[BT][96];     // [y(32) | h0(64)]
  __shared__ __align__(16) float z1buf[BT][160];   // [h0|h1] logical 128, stride 20 per 16
  __shared__ __align__(16) float gpart[BT][G4][4];
  __shared__ __align__(16) float wcs[16][32];      // folded conv+bn, [tap][chan]
  __shared__ float xwin[3][BT][DIN];

  const int tid = threadIdx.x;
  const int b0  = blockIdx.x * BT;
  const int p   = tid & 7;
  const int rg  = tid >> 3;
  const int r0  = rg*2, r1 = rg*2 + 1;
  const int abt = tid >> 6;
  const int au  = tid & 63;

  // ---- per-thread weights: 2 rows x (12 of K0=96) and 2 rows x (16 of K1=128)
  float w0[2][12], w1[2][16];
#pragma unroll
  for (int r = 0; r < 2; ++r) {
    const int row = rg*2 + r;
#pragma unroll
    for (int k = 0; k < 12; ++k) {
      const int g = 12*p + k;
      w0[r][k] = (g < 32) ? wih0[row*32 + g] : whh0[row*64 + (g-32)];
    }
#pragma unroll
    for (int k = 0; k < 16; ++k) {
      const int g = 16*p + k;
      w1[r][k] = (g < 64) ? wih1[row*64 + g] : whh1[row*64 + (g-64)];
    }
  }

  float b0r[4] = {0,0,0,0}, b1r[4] = {0,0,0,0};
  if (tid < 512) {
#pragma unroll
    for (int g = 0; g < 4; ++g) {
      b0r[g] = bih0[au + 64*g] + bhh0[au + 64*g];
      b1r[g] = bih1[au + 64*g] + bhh1[au + 64*g];
    }
  }

  if (tid < 32) {
    float s = bn_g[tid] * rsqrtf(bn_v[tid] + 1e-5f);
#pragma unroll
    for (int i = 0; i < 5; ++i)
#pragma unroll
      for (int tau = 0; tau < 3; ++tau)
        wcs[tau*5 + i][tid] = conv_w[tid*15 + i*3 + tau] * s;
    wcs[15][tid] = (conv_b[tid] - bn_m[tid]) * s + bn_b[tid];
  }

  for (int i = tid; i < BT*160; i += 1024) ((float*)z1buf)[i] = 0.f;
  if (tid < 512) zbuf[abt][32 + au] = 0.f;

  const int xb = tid / 5, xi = tid % 5;
  if (tid < 40) {
    xwin[2][xb][xi] = 0.f;                                     // t=-1 pad
    xwin[0][xb][xi] = xg[((size_t)(b0+xb)*SEQ + 0)*DIN + xi];  // x[0]
  }
  float xpref = 0.f;
  if (tid < 40) xpref = xg[((size_t)(b0+xb)*SEQ + 1)*DIN + xi];

  int sp = 2, scu = 0, snx = 1;
  float c0 = 0.f, c1 = 0.f, h1v = 0.f;
  __syncthreads();

  for (int t = 0; t < SEQ; ++t) {
    if (tid < 40) xwin[snx][xb][xi] = xpref;
    __syncthreads();  // S1
    if (tid < 40) {
      const int tq = t + 2;
      xpref = (tq < SEQ) ? xg[((size_t)(b0+xb)*SEQ + tq)*DIN + xi] : 0.f;
    }
    if (tid < 256) {  // conv+bn+relu
      const int bb = tid >> 5, cc = tid & 31;
      float s = wcs[15][cc];
#pragma unroll
      for (int i = 0; i < 5; ++i) {
        s += wcs[i][cc]    * xwin[sp][bb][i];
        s += wcs[5+i][cc]  * xwin[scu][bb][i];
        s += wcs[10+i][cc] * xwin[snx][bb][i];
      }
      zbuf[bb][cc] = fmaxf(s, 0.f);
    }
    __syncthreads();  // S2

    // ---- L0 gates: outer K-chunk, inner batch (weight chunk amortized 8x)
    {
      float a0[BT], a1[BT];
#pragma unroll
      for (int b = 0; b < BT; ++b) { a0[b] = 0.f; a1[b] = 0.f; }
#pragma unroll
      for (int c = 0; c < 3; ++c) {
        const float u0 = w0[0][4*c+0], u1 = w0[0][4*c+1], u2 = w0[0][4*c+2], u3 = w0[0][4*c+3];
        const float v0 = w0[1][4*c+0], v1 = w0[1][4*c+1], v2 = w0[1][4*c+2], v3 = w0[1][4*c+3];
#pragma unroll
        for (int b = 0; b < BT; ++b) {
          float4 z = *(const float4*)(&zbuf[b][12*p + 4*c]);
          a0[b] += u0*z.x + u1*z.y + u2*z.z + u3*z.w;
          a1[b] += v0*z.x + v1*z.y + v2*z.z + v3*z.w;
        }
      }
#pragma unroll
      for (int b = 0; b < BT; ++b) {
        a0[b] += __shfl_xor(a0[b], 4, 64);
        a1[b] += __shfl_xor(a1[b], 4, 64);
      }
      if (p < 4) {
#pragma unroll
        for (int b = 0; b < BT; ++b) { gpart[b][r0][p] = a0[b]; gpart[b][r1][p] = a1[b]; }
      }
    }
    __syncthreads();  // S3
    if (tid < 512) {  // L0 activation
      float g4[4];
#pragma unroll
      for (int g = 0; g < 4; ++g) {
        const float4* gp = (const float4*)(&gpart[abt][au + 64*g][0]);
        float4 A = gp[0];
        g4[g] = A.x + A.y + A.z + A.w + b0r[g];
      }
      c0 = fsig(g4[1])*c0 + fsig(g4[0])*ftanh(g4[2]);
      float h0 = fsig(g4[3])*ftanh(c0);
      zbuf[abt][32 + au] = h0;
      z1buf[abt][20*(au>>4) + (au&15)] = h0;
    }
    __syncthreads();  // S4

    // ---- L1 gates
    {
      float a0[BT], a1[BT];
#pragma unroll
      for (int b = 0; b < BT; ++b) { a0[b] = 0.f; a1[b] = 0.f; }
#pragma unroll
      for (int c = 0; c < 4; ++c) {
        const float u0 = w1[0][4*c+0], u1 = w1[0][4*c+1], u2 = w1[0][4*c+2], u3 = w1[0][4*c+3];
        const float v0 = w1[1][4*c+0], v1 = w1[1][4*c+1], v2 = w1[1][4*c+2], v3 = w1[1][4*c+3];
#pragma unroll
        for (int b = 0; b < BT; ++b) {
          float4 z = *(const float4*)(&z1buf[b][20*p + 4*c]);
          a0[b] += u0*z.x + u1*z.y + u2*z.z + u3*z.w;
          a1[b] += v0*z.x + v1*z.y + v2*z.z + v3*z.w;
        }
      }
#pragma unroll
      for (int b = 0; b < BT; ++b) {
        a0[b] += __shfl_xor(a0[b], 4, 64);
        a1[b] += __shfl_xor(a1[b], 4, 64);
      }
      if (p < 4) {
#pragma unroll
        for (int b = 0; b < BT; ++b) { gpart[b][r0][p] = a0[b]; gpart[b][r1][p] = a1[b]; }
      }
    }
    __syncthreads();  // S5
    if (tid < 512) {  // L1 activation
      float g4[4];
#pragma unroll
      for (int g = 0; g < 4; ++g) {
        const float4* gp = (const float4*)(&gpart[abt][au + 64*g][0]);
        float4 A = gp[0];
        g4[g] = A.x + A.y + A.z + A.w + b1r[g];
      }
      c1 = fsig(g4[1])*c1 + fsig(g4[0])*ftanh(g4[2]);
      h1v = fsig(g4[3])*ftanh(c1);
      z1buf[abt][20*(4 + (au>>4)) + (au&15)] = h1v;
    }
    { int tmp = sp; sp = scu; scu = snx; snx = tmp; }
  }

  if (tid < 512) {
    const size_t gb = (size_t)(b0 + abt);
    out[gb*COMB + au]        = h1v;
    out[OUTC + gb*COMB + au] = h1v;
  }
}

// ===================== VQ stream =====================
__global__ __launch_bounds__(1024)
__attribute__((amdgpu_waves_per_eu(4, 4)))
void vq_stream_kernel(const float* __restrict__ xg,
                      const float* __restrict__ wih0, const float* __restrict__ whh0,
                      const float* __restrict__ bih0, const float* __restrict__ bhh0,
                      const float* __restrict__ wih1, const float* __restrict__ whh1,
                      const float* __restrict__ bih1, const float* __restrict__ bhh1,
                      const float* __restrict__ proj_w, const float* __restrict__ proj_b,
                      const float* __restrict__ codebook,
                      float* __restrict__ out, float* __restrict__ ws_f,
                      int* __restrict__ ws_hist)
{
  __shared__ __align__(16) float zh[BT][96];       // h0 logical 64, stride 12 per 8
  __shared__ __align__(16) float z1buf[BT][160];   // [h0|h1] logical 128, stride 20 per 16
  __shared__ __align__(16) float gpart[BT][G4][4];
  __shared__ __align__(16) float pbuf[BT][EDIM];
  __shared__ float xbuf[2][BT][DIN];

  const int tid = threadIdx.x;
  const int b0  = blockIdx.x * BT;
  const int p   = tid & 7;
  const int rg  = tid >> 3;
  const int r0  = rg*2, r1 = rg*2 + 1;
  const int abt = tid >> 6;
  const int au  = tid & 63;

  float w0[2][8], w1[2][16];
#pragma unroll
  for (int r = 0; r < 2; ++r) {
    const int row = rg*2 + r;
#pragma unroll
    for (int j = 0; j < 8; ++j) w0[r][j] = whh0[row*64 + 8*p + j];
#pragma unroll
    for (int k = 0; k < 16; ++k) {
      const int g = 16*p + k;
      w1[r][k] = (g < 64) ? wih1[row*64 + g] : whh1[row*64 + (g-64)];
    }
  }

  float b0r[4] = {0,0,0,0}, b1r[4] = {0,0,0,0}, xw[4][5];
  if (tid < 512) {
#pragma unroll
    for (int g = 0; g < 4; ++g) {
      const int row = au + 64*g;
      b0r[g] = bih0[row] + bhh0[row];
      b1r[g] = bih1[row] + bhh1[row];
#pragma unroll
      for (int i = 0; i < 5; ++i) xw[g][i] = wih0[row*5 + i];
    }
  }

  for (int i = tid; i < BT*160; i += 1024) ((float*)z1buf)[i] = 0.f;
  if (tid < BT*96) ((float*)zh)[tid] = 0.f;

  const int xb = tid / 5, xi = tid % 5;
  if (tid < 40) xbuf[0][xb][xi] = xg[((size_t)(b0+xb)*SEQ + 0)*DIN + xi];
  float xpref = 0.f;
  if (tid < 40) xpref = xg[((size_t)(b0+xb)*SEQ + 1)*DIN + xi];

  float c0 = 0.f, c1 = 0.f;
  __syncthreads();

  for (int t = 0; t < SEQ; ++t) {
    if (tid < 40) xbuf[(t+1)&1][xb][xi] = xpref;
    if (tid < 40) {
      const int tq = t + 2;
      xpref = (tq < SEQ) ? xg[((size_t)(b0+xb)*SEQ + tq)*DIN + xi] : 0.f;
    }
    // ---- L0 gates (h-part only; x-part added in activation)
    {
      float a0[BT], a1[BT];
#pragma unroll
      for (int b = 0; b < BT; ++b) { a0[b] = 0.f; a1[b] = 0.f; }
#pragma unroll
      for (int c = 0; c < 2; ++c) {
        const float u0 = w0[0][4*c+0], u1 = w0[0][4*c+1], u2 = w0[0][4*c+2], u3 = w0[0][4*c+3];
        const float v0 = w0[1][4*c+0], v1 = w0[1][4*c+1], v2 = w0[1][4*c+2], v3 = w0[1][4*c+3];
#pragma unroll
        for (int b = 0; b < BT; ++b) {
          float4 z = *(const float4*)(&zh[b][12*p + 4*c]);
          a0[b] += u0*z.x + u1*z.y + u2*z.z + u3*z.w;
          a1[b] += v0*z.x + v1*z.y + v2*z.z + v3*z.w;
        }
      }
#pragma unroll
      for (int b = 0; b < BT; ++b) {
        a0[b] += __shfl_xor(a0[b], 4, 64);
        a1[b] += __shfl_xor(a1[b], 4, 64);
      }
      if (p < 4) {
#pragma unroll
        for (int b = 0; b < BT; ++b) { gpart[b][r0][p] = a0[b]; gpart[b][r1][p] = a1[b]; }
      }
    }
    __syncthreads();  // Sa
    if (tid < 512) {  // L0 activation (+ x-part)
      float xv[5];
#pragma unroll
      for (int i = 0; i < 5; ++i) xv[i] = xbuf[t&1][abt][i];
      float g4[4];
#pragma unroll
      for (int g = 0; g < 4; ++g) {
        const float4* gp = (const float4*)(&gpart[abt][au + 64*g][0]);
        float4 A = gp[0];
        g4[g] = A.x + A.y + A.z + A.w + b0r[g]
              + xw[g][0]*xv[0] + xw[g][1]*xv[1] + xw[g][2]*xv[2]
              + xw[g][3]*xv[3] + xw[g][4]*xv[4];
      }
      c0 = fsig(g4[1])*c0 + fsig(g4[0])*ftanh(g4[2]);
      float h0 = fsig(g4[3])*ftanh(c0);
      zh[abt][12*(au>>3) + (au&7)] = h0;
      z1buf[abt][20*(au>>4) + (au&15)] = h0;
    }
    __syncthreads();  // Sb
    // ---- L1 gates
    {
      float a0[BT], a1[BT];
#pragma unroll
      for (int b = 0; b < BT; ++b) { a0[b] = 0.f; a1[b] = 0.f; }
#pragma unroll
      for (int c = 0; c < 4; ++c) {
        const float u0 = w1[0][4*c+0], u1 = w1[0][4*c+1], u2 = w1[0][4*c+2], u3 = w1[0][4*c+3];
        const float v0 = w1[1][4*c+0], v1 = w1[1][4*c+1], v2 = w1[1][4*c+2], v3 = w1[1][4*c+3];
#pragma unroll
        for (int b = 0; b < BT; ++b) {
          float4 z = *(const float4*)(&z1buf[b][20*p + 4*c]);
          a0[b] += u0*z.x + u1*z.y + u2*z.z + u3*z.w;
          a1[b] += v0*z.x + v1*z.y + v2*z.z + v3*z.w;
        }
      }
#pragma unroll
      for (int b = 0; b < BT; ++b) {
        a0[b] += __shfl_xor(a0[b], 4, 64);
        a1[b] += __shfl_xor(a1[b], 4, 64);
      }
      if (p < 4) {
#pragma unroll
        for (int b = 0; b < BT; ++b) { gpart[b][r0][p] = a0[b]; gpart[b][r1][p] = a1[b]; }
      }
    }
    __syncthreads();  // Sc
    if (tid < 512) {  // L1 activation
      float g4[4];
#pragma unroll
      for (int g = 0; g < 4; ++g) {
        const float4* gp = (const float4*)(&gpart[abt][au + 64*g][0]);
        float4 A = gp[0];
        g4[g] = A.x + A.y + A.z + A.w + b1r[g];
      }
      c1 = fsig(g4[1])*c1 + fsig(g4[0])*ftanh(g4[2]);
      float h1 = fsig(g4[3])*ftanh(c1);
      z1buf[abt][20*(4 + (au>>4)) + (au&15)] = h1;
    }
    __syncthreads();  // Sd
  }

  // ---- projection
  if (tid < 256) {
    const int bb = tid >> 5, e = tid & 31;
    float s = proj_b[e];
    const float* pw = proj_w + e*HID;
#pragma unroll
    for (int k = 0; k < HID; ++k)
      s += z1buf[bb][20*(4 + (k>>4)) + (k&15)] * pw[k];
    pbuf[bb][e] = s;
  }
  __syncthreads();

  // ---- distances + argmin (wave per batch)
  if (tid < 512) {
    const int bb = abt, n = au;
    const float* cbn = codebook + n*EDIM;
    float d = 0.f;
#pragma unroll
    for (int k = 0; k < EDIM; ++k) { float df = pbuf[bb][k] - cbn[k]; d += df*df; }
    int bi = n;
#pragma unroll
    for (int off = 32; off > 0; off >>= 1) {
      float od = __shfl_down(d, off, 64);
      int   oi = __shfl_down(bi, off, 64);
      if (od < d || (od == d && oi < bi)) { d = od; bi = oi; }
    }
    bi = __shfl(bi, 0, 64);

    float lv = 0.f;
    if (n < EDIM) {
      float q = codebook[bi*EDIM + n];
      const size_t gb = (size_t)(b0 + bb);
      out[gb*COMB + HID + n]        = q;
      out[OUTC + gb*COMB + HID + n] = q;
      float df = q - pbuf[bb][n];
      lv = df * df;
    }
#pragma unroll
    for (int off = 32; off > 0; off >>= 1) lv += __shfl_down(lv, off, 64);
    if (n == 0) {
      atomicAdd(ws_f, lv);
      atomicAdd(&ws_hist[bi], 1);
    }
  }
}

// ===================== scalars =====================
__global__ void zero_ws_kernel(float* ws_f, int* ws_hist) {
  const int t = threadIdx.x;
  if (t == 0) ws_f[0] = 0.f;
  if (t < NEMB) ws_hist[t] = 0;
}

__global__ void vq_finalize_kernel(const float* __restrict__ ws_f,
                                   const int* __restrict__ ws_hist,
                                   float* __restrict__ out) {
  const int t = threadIdx.x;  // 64 threads = 1 wave
  float p = (float)ws_hist[t] * (1.0f / (float)B_TOT);
  float e = -p * logf(p + 1e-10f);
#pragma unroll
  for (int off = 32; off > 0; off >>= 1) e += __shfl_down(e, off, 64);
  if (t == 0) {
    float mse = ws_f[0] * (1.0f / (float)(B_TOT * EDIM));
    out[2*OUTC + 0] = mse * 1.01f;   // q_loss + 0.01*e_loss (identical fwd)
    out[2*OUTC + 1] = expf(e);       // perplexity
  }
}

extern "C" void kernel_launch(void* const* d_in, const int* in_sizes, int n_in,
                              void* d_out, int out_size, void* d_ws, size_t ws_size,
                              hipStream_t stream) {
  const float* x        = (const float*)d_in[0];
  const float* conv_w   = (const float*)d_in[1];
  const float* conv_b   = (const float*)d_in[2];
  const float* bn_g     = (const float*)d_in[3];
  const float* bn_b     = (const float*)d_in[4];
  const float* bn_m     = (const float*)d_in[5];
  const float* bn_v     = (const float*)d_in[6];
  const float* cnn0_wih = (const float*)d_in[7];
  const float* cnn0_whh = (const float*)d_in[8];
  const float* cnn0_bih = (const float*)d_in[9];
  const float* cnn0_bhh = (const float*)d_in[10];
  const float* cnn1_wih = (const float*)d_in[11];
  const float* cnn1_whh = (const float*)d_in[12];
  const float* cnn1_bih = (const float*)d_in[13];
  const float* cnn1_bhh = (const float*)d_in[14];
  const float* vq0_wih  = (const float*)d_in[15];
  const float* vq0_whh  = (const float*)d_in[16];
  const float* vq0_bih  = (const float*)d_in[17];
  const float* vq0_bhh  = (const float*)d_in[18];
  const float* vq1_wih  = (const float*)d_in[19];
  const float* vq1_whh  = (const float*)d_in[20];
  const float* vq1_bih  = (const float*)d_in[21];
  const float* vq1_bhh  = (const float*)d_in[22];
  const float* proj_w   = (const float*)d_in[23];
  const float* proj_b   = (const float*)d_in[24];
  const float* codebook = (const float*)d_in[25];

  float* out     = (float*)d_out;
  float* ws_f    = (float*)d_ws;
  int*   ws_hist = (int*)d_ws + 16;

  hipLaunchKernelGGL(zero_ws_kernel, dim3(1), dim3(64), 0, stream, ws_f, ws_hist);
  hipLaunchKernelGGL(cnn_stream_kernel, dim3(B_TOT/BT), dim3(1024), 0, stream,
                     x, conv_w, conv_b, bn_g, bn_b, bn_m, bn_v,
                     cnn0_wih, cnn0_whh, cnn0_bih, cnn0_bhh,
                     cnn1_wih, cnn1_whh, cnn1_bih, cnn1_bhh, out);
  hipLaunchKernelGGL(vq_stream_kernel, dim3(B_TOT/BT), dim3(1024), 0, stream,
                     x, vq0_wih, vq0_whh, vq0_bih, vq0_bhh,
                     vq1_wih, vq1_whh, vq1_bih, vq1_bhh,
                     proj_w, proj_b, codebook, out, ws_f, ws_hist);
  hipLaunchKernelGGL(vq_finalize_kernel, dim3(1), dim3(64), 0, stream, ws_f, ws_hist, out);
}

// Round 4
// 1708.753 us; speedup vs baseline: 3.4127x; 3.4127x over previous
//
#include <hip/hip_runtime.h>
#include <math.h>
#include <stdint.h>

#define B_TOT 2048
#define SEQ   512
#define DIN   5
#define HID   64
#define EDIM  32
#define NEMB  64
#define BT    16
#define NBLK_STREAM 128
#define COMB  96
#define OUTC  (B_TOT*COMB)

typedef __attribute__((ext_vector_type(8))) short short8;    // 8 bf16 = 4 VGPRs
typedef __attribute__((ext_vector_type(4))) float float4v;

__device__ __forceinline__ float fsig(float x){ return 1.0f/(1.0f + __expf(-x)); }
__device__ __forceinline__ float ftanh(float x){
  float xc = fminf(fmaxf(x, -15.f), 15.f);
  float e  = __expf(-2.f*xc);
  return (1.f - e) / (1.f + e);
}
__device__ __forceinline__ short f2bf(float f){        // RNE fp32 -> bf16
  uint32_t u = __float_as_uint(f);
  uint32_t r = u + 0x7FFFu + ((u >> 16) & 1u);
  return (short)(r >> 16);
}
__device__ __forceinline__ float bf2f(short h){
  return __uint_as_float(((uint32_t)(uint16_t)h) << 16);
}
__device__ __forceinline__ void f2bf2(float f, short& hi, short& lo){
  hi = f2bf(f);
  lo = f2bf(f - bf2f(hi));
}
#define MFMA(a,b,c) __builtin_amdgcn_mfma_f32_16x16x32_bf16((a),(b),(c),0,0,0)

// Fused dual-stream kernel: blocks [0,128) = CNN stream, [128,256) = VQ stream.
// 512 threads = 8 waves. Wave w computes gate-row tiles 2w,2w+1 via MFMA.
// B-frag LDS layout: Z[kt][quad][n][j] bf16 (hi/lo arrays), lane(n=lane&15,
// quad=lane>>4) reads 8 contiguous bf16 = 1 ds_read_b128 per ktile per half.
__global__ __launch_bounds__(512)
__attribute__((amdgpu_waves_per_eu(2, 2)))
void fused_kernel(const float* __restrict__ xg,
                  const float* __restrict__ conv_w, const float* __restrict__ conv_b,
                  const float* __restrict__ bn_g, const float* __restrict__ bn_b,
                  const float* __restrict__ bn_m, const float* __restrict__ bn_v,
                  const float* __restrict__ cnn0_wih, const float* __restrict__ cnn0_whh,
                  const float* __restrict__ cnn0_bih, const float* __restrict__ cnn0_bhh,
                  const float* __restrict__ cnn1_wih, const float* __restrict__ cnn1_whh,
                  const float* __restrict__ cnn1_bih, const float* __restrict__ cnn1_bhh,
                  const float* __restrict__ vq0_wih, const float* __restrict__ vq0_whh,
                  const float* __restrict__ vq0_bih, const float* __restrict__ vq0_bhh,
                  const float* __restrict__ vq1_wih, const float* __restrict__ vq1_whh,
                  const float* __restrict__ vq1_bih, const float* __restrict__ vq1_bhh,
                  const float* __restrict__ proj_w, const float* __restrict__ proj_b,
                  const float* __restrict__ codebook,
                  float* __restrict__ out, float* __restrict__ ws_f,
                  int* __restrict__ ws_hist)
{
  __shared__ __align__(16) short Z0hi[3][4][BT][8], Z0lo[3][4][BT][8];  // K=96 operand
  __shared__ __align__(16) short Z1hi[4][4][BT][8], Z1lo[4][4][BT][8];  // K=128 operand
  __shared__ __align__(16) float Gbuf[BT][264];                          // gates, pad 264
  __shared__ __align__(16) float hfin[BT][HID];                          // vq final h1
  __shared__ __align__(16) float pbuf[BT][EDIM];
  __shared__ float wcs[16][32];                                          // folded conv+bn
  __shared__ float xwin[3][BT][DIN];

  const int tid  = threadIdx.x;
  const bool is_cnn = (blockIdx.x < NBLK_STREAM);
  const int b0   = (is_cnn ? blockIdx.x : blockIdx.x - NBLK_STREAM) * BT;
  const int w    = tid >> 6;
  const int lane = tid & 63;
  const int n16  = lane & 15;     // MFMA: B col / D col; act: batch
  const int quad = lane >> 4;     // MFMA: k-quad; D row group

  const float* wih0 = is_cnn ? cnn0_wih : vq0_wih;
  const float* whh0 = is_cnn ? cnn0_whh : vq0_whh;
  const float* bih0 = is_cnn ? cnn0_bih : vq0_bih;
  const float* bhh0 = is_cnn ? cnn0_bhh : vq0_bhh;
  const float* wih1 = is_cnn ? cnn1_wih : vq1_wih;
  const float* whh1 = is_cnn ? cnn1_whh : vq1_whh;
  const float* bih1 = is_cnn ? cnn1_bih : vq1_bih;
  const float* bhh1 = is_cnn ? cnn1_bhh : vq1_bhh;

  // ---- static A-fragments (weights) as bf16 hi/lo.
  // A[m=lane&15 -> row 16T+m][k=quad*8+j]  (verified gfx950 A-operand layout)
  short8 Ah0[2][3], Al0[2][3], Ah1[2][4], Al1[2][4];
#pragma unroll
  for (int T = 0; T < 2; ++T) {
    const int row = 16*(2*w + T) + n16;
#pragma unroll
    for (int kt = 0; kt < 3; ++kt) {
      short8 vh, vl;
#pragma unroll
      for (int j = 0; j < 8; ++j) {
        const int g = kt*32 + quad*8 + j;
        float wv;
        if (is_cnn) wv = (g < 32) ? wih0[row*32 + g] : whh0[row*64 + (g-32)];
        else        wv = (g < 5) ? wih0[row*5 + g] : (g < 32 ? 0.f : whh0[row*64 + (g-32)]);
        short hi, lo; f2bf2(wv, hi, lo); vh[j] = hi; vl[j] = lo;
      }
      Ah0[T][kt] = vh; Al0[T][kt] = vl;
    }
#pragma unroll
    for (int kt = 0; kt < 4; ++kt) {
      short8 vh, vl;
#pragma unroll
      for (int j = 0; j < 8; ++j) {
        const int g = kt*32 + quad*8 + j;
        float wv = (g < 64) ? wih1[row*64 + g] : whh1[row*64 + (g-64)];
        short hi, lo; f2bf2(wv, hi, lo); vh[j] = hi; vl[j] = lo;
      }
      Ah1[T][kt] = vh; Al1[T][kt] = vl;
    }
  }

  // ---- act-thread identity: thread owns units u = 8w + 2*(lane>>4) + {0,1}, batch n16
  const int uu0 = 8*w + 2*quad, uu1 = uu0 + 1;
  float bb0[2][4], bb1[2][4];
#pragma unroll
  for (int g = 0; g < 4; ++g) {
    bb0[0][g] = bih0[uu0 + 64*g] + bhh0[uu0 + 64*g];
    bb0[1][g] = bih0[uu1 + 64*g] + bhh0[uu1 + 64*g];
    bb1[0][g] = bih1[uu0 + 64*g] + bhh1[uu0 + 64*g];
    bb1[1][g] = bih1[uu1 + 64*g] + bhh1[uu1 + 64*g];
  }

  // ---- zero-init Z operand arrays (pads stay zero forever)
  for (int i2 = tid; i2 < 3*4*BT*8/2; i2 += 512) { ((uint32_t*)Z0hi)[i2] = 0; ((uint32_t*)Z0lo)[i2] = 0; }
  for (int i2 = tid; i2 < 4*4*BT*8/2; i2 += 512) { ((uint32_t*)Z1hi)[i2] = 0; ((uint32_t*)Z1lo)[i2] = 0; }

  const int xn = tid / 5, xi = tid % 5;
  float xnxt = 0.f, xcur = 0.f;
  if (is_cnn) {
    if (tid < 32) {
      float s = bn_g[tid] * rsqrtf(bn_v[tid] + 1e-5f);
#pragma unroll
      for (int i = 0; i < 5; ++i)
#pragma unroll
        for (int tau = 0; tau < 3; ++tau)
          wcs[tau*5 + i][tid] = conv_w[tid*15 + i*3 + tau] * s;
      wcs[15][tid] = (conv_b[tid] - bn_m[tid]) * s + bn_b[tid];
    }
    if (tid < 80) {
      xwin[2][xn][xi] = 0.f;                                      // t=-1 pad
      xwin[0][xn][xi] = xg[((size_t)(b0+xn)*SEQ + 0)*DIN + xi];
      xnxt            = xg[((size_t)(b0+xn)*SEQ + 1)*DIN + xi];
    }
  } else {
    if (tid < 80) {
      xcur = xg[((size_t)(b0+xn)*SEQ + 0)*DIN + xi];
      xnxt = xg[((size_t)(b0+xn)*SEQ + 1)*DIN + xi];
    }
  }

  float c0[2] = {0,0}, c1[2] = {0,0}, h1v[2] = {0,0};
  int sp = 2, scu = 0, snx = 1;
  __syncthreads();

  for (int t = 0; t < SEQ; ++t) {
    if (is_cnn) {
      if (tid < 80) xwin[snx][xn][xi] = xnxt;
    } else {
      if (tid < 80) { short hi, lo; f2bf2(xcur, hi, lo);
                      Z0hi[0][0][xn][xi] = hi; Z0lo[0][0][xn][xi] = lo; }
    }
    __syncthreads();  // S1
    float xfut = 0.f;
    if (tid < 80) { const int tq = t + 2;
                    if (tq < SEQ) xfut = xg[((size_t)(b0+xn)*SEQ + tq)*DIN + xi]; }
    if (is_cnn) {   // conv+bn+relu -> Z0 k=cc; all 512 threads: cc=tid>>4, cn=tid&15
      const int cc = tid >> 4, cn = tid & 15;
      float s = wcs[15][cc];
#pragma unroll
      for (int i = 0; i < 5; ++i)
        s += wcs[i][cc]*xwin[sp][cn][i] + wcs[5+i][cc]*xwin[scu][cn][i]
           + wcs[10+i][cc]*xwin[snx][cn][i];
      s = fmaxf(s, 0.f);
      short hi, lo; f2bf2(s, hi, lo);
      Z0hi[0][cc>>3][cn][cc&7] = hi; Z0lo[0][cc>>3][cn][cc&7] = lo;
    }
    __syncthreads();  // S2

    // ---- L0 MFMA: G = W0 x Z0, bf16x3
    {
      float4v a0 = {0,0,0,0}, a1 = {0,0,0,0};
#pragma unroll
      for (int kt = 0; kt < 3; ++kt) {
        short8 bh = *(const short8*)&Z0hi[kt][quad][n16][0];
        short8 bl = *(const short8*)&Z0lo[kt][quad][n16][0];
        a0 = MFMA(Ah0[0][kt], bh, a0); a0 = MFMA(Ah0[0][kt], bl, a0); a0 = MFMA(Al0[0][kt], bh, a0);
        a1 = MFMA(Ah0[1][kt], bh, a1); a1 = MFMA(Ah0[1][kt], bl, a1); a1 = MFMA(Al0[1][kt], bh, a1);
      }
      // D: row = 16T + 4*quad + reg, col = n16
      *(float4v*)&Gbuf[n16][16*(2*w+0) + 4*quad] = a0;
      *(float4v*)&Gbuf[n16][16*(2*w+1) + 4*quad] = a1;
    }
    __syncthreads();  // S3
    // ---- L0 act
    {
      const int us[2] = {uu0, uu1};
#pragma unroll
      for (int jj = 0; jj < 2; ++jj) {
        const int u = us[jj];
        float g0 = Gbuf[n16][u]       + bb0[jj][0];
        float g1 = Gbuf[n16][u + 64]  + bb0[jj][1];
        float g2 = Gbuf[n16][u + 128] + bb0[jj][2];
        float g3 = Gbuf[n16][u + 192] + bb0[jj][3];
        c0[jj] = fsig(g1)*c0[jj] + fsig(g0)*ftanh(g2);
        float h0 = fsig(g3)*ftanh(c0[jj]);
        short hi, lo; f2bf2(h0, hi, lo);
        Z1hi[u>>5][(u>>3)&3][n16][u&7] = hi;          // L1 operand, k=u
        Z1lo[u>>5][(u>>3)&3][n16][u&7] = lo;
        const int k2 = 32 + u;                         // L0 operand next step, k=32+u
        Z0hi[k2>>5][(k2>>3)&3][n16][k2&7] = hi;
        Z0lo[k2>>5][(k2>>3)&3][n16][k2&7] = lo;
      }
    }
    __syncthreads();  // S4
    // ---- L1 MFMA: G = W1 x Z1
    {
      float4v a0 = {0,0,0,0}, a1 = {0,0,0,0};
#pragma unroll
      for (int kt = 0; kt < 4; ++kt) {
        short8 bh = *(const short8*)&Z1hi[kt][quad][n16][0];
        short8 bl = *(const short8*)&Z1lo[kt][quad][n16][0];
        a0 = MFMA(Ah1[0][kt], bh, a0); a0 = MFMA(Ah1[0][kt], bl, a0); a0 = MFMA(Al1[0][kt], bh, a0);
        a1 = MFMA(Ah1[1][kt], bh, a1); a1 = MFMA(Ah1[1][kt], bl, a1); a1 = MFMA(Al1[1][kt], bh, a1);
      }
      *(float4v*)&Gbuf[n16][16*(2*w+0) + 4*quad] = a0;
      *(float4v*)&Gbuf[n16][16*(2*w+1) + 4*quad] = a1;
    }
    __syncthreads();  // S5
    // ---- L1 act
    {
      const int us[2] = {uu0, uu1};
#pragma unroll
      for (int jj = 0; jj < 2; ++jj) {
        const int u = us[jj];
        float g0 = Gbuf[n16][u]       + bb1[jj][0];
        float g1 = Gbuf[n16][u + 64]  + bb1[jj][1];
        float g2 = Gbuf[n16][u + 128] + bb1[jj][2];
        float g3 = Gbuf[n16][u + 192] + bb1[jj][3];
        c1[jj] = fsig(g1)*c1[jj] + fsig(g0)*ftanh(g2);
        float h1 = fsig(g3)*ftanh(c1[jj]);
        short hi, lo; f2bf2(h1, hi, lo);
        const int k3 = 64 + u;                         // L1 operand next step
        Z1hi[k3>>5][(k3>>3)&3][n16][k3&7] = hi;
        Z1lo[k3>>5][(k3>>3)&3][n16][k3&7] = lo;
        if (is_cnn) h1v[jj] = h1;
        else if (t == SEQ-1) hfin[n16][u] = h1;
      }
    }
    if (is_cnn) { int tmp = sp; sp = scu; scu = snx; snx = tmp; xnxt = xfut; }
    else        { xcur = xnxt; xnxt = xfut; }
  }

  if (is_cnn) {
    const size_t gb = (size_t)(b0 + n16);
    out[gb*COMB + uu0]        = h1v[0];
    out[OUTC + gb*COMB + uu0] = h1v[0];
    out[gb*COMB + uu1]        = h1v[1];
    out[OUTC + gb*COMB + uu1] = h1v[1];
  } else {
    __syncthreads();
    {  // projection: vq_proj[16][32]
      const int pn = tid >> 5, pe = tid & 31;
      float s = proj_b[pe];
      const float* pw = proj_w + pe*HID;
#pragma unroll
      for (int k = 0; k < HID; ++k) s += hfin[pn][k] * pw[k];
      pbuf[pn][pe] = s;
    }
    __syncthreads();
    // argmin: wave w handles batches 2w, 2w+1; lane = code index
#pragma unroll
    for (int rep = 0; rep < 2; ++rep) {
      const int bb = 2*w + rep;
      const int nn = lane;
      const float* cbn = codebook + nn*EDIM;
      float d = 0.f;
#pragma unroll
      for (int k = 0; k < EDIM; ++k) { float df = pbuf[bb][k] - cbn[k]; d += df*df; }
      int bi = nn;
#pragma unroll
      for (int off = 32; off > 0; off >>= 1) {
        float od = __shfl_down(d, off, 64);
        int   oi = __shfl_down(bi, off, 64);
        if (od < d || (od == d && oi < bi)) { d = od; bi = oi; }
      }
      bi = __shfl(bi, 0, 64);
      float lv = 0.f;
      if (nn < EDIM) {
        float q = codebook[bi*EDIM + nn];
        const size_t gb = (size_t)(b0 + bb);
        out[gb*COMB + HID + nn]        = q;
        out[OUTC + gb*COMB + HID + nn] = q;
        float df = q - pbuf[bb][nn];
        lv = df*df;
      }
#pragma unroll
      for (int off = 32; off > 0; off >>= 1) lv += __shfl_down(lv, off, 64);
      if (nn == 0) { atomicAdd(ws_f, lv); atomicAdd(&ws_hist[bi], 1); }
    }
  }
}

// ===================== scalars =====================
__global__ void zero_ws_kernel(float* ws_f, int* ws_hist) {
  const int t = threadIdx.x;
  if (t == 0) ws_f[0] = 0.f;
  if (t < NEMB) ws_hist[t] = 0;
}

__global__ void vq_finalize_kernel(const float* __restrict__ ws_f,
                                   const int* __restrict__ ws_hist,
                                   float* __restrict__ out) {
  const int t = threadIdx.x;  // 64 threads = 1 wave
  float p = (float)ws_hist[t] * (1.0f / (float)B_TOT);
  float e = -p * logf(p + 1e-10f);
#pragma unroll
  for (int off = 32; off > 0; off >>= 1) e += __shfl_down(e, off, 64);
  if (t == 0) {
    float mse = ws_f[0] * (1.0f / (float)(B_TOT * EDIM));
    out[2*OUTC + 0] = mse * 1.01f;   // q_loss + 0.01*e_loss (identical fwd)
    out[2*OUTC + 1] = expf(e);       // perplexity
  }
}

extern "C" void kernel_launch(void* const* d_in, const int* in_sizes, int n_in,
                              void* d_out, int out_size, void* d_ws, size_t ws_size,
                              hipStream_t stream) {
  const float* x        = (const float*)d_in[0];
  const float* conv_w   = (const float*)d_in[1];
  const float* conv_b   = (const float*)d_in[2];
  const float* bn_g     = (const float*)d_in[3];
  const float* bn_b     = (const float*)d_in[4];
  const float* bn_m     = (const float*)d_in[5];
  const float* bn_v     = (const float*)d_in[6];
  const float* cnn0_wih = (const float*)d_in[7];
  const float* cnn0_whh = (const float*)d_in[8];
  const float* cnn0_bih = (const float*)d_in[9];
  const float* cnn0_bhh = (const float*)d_in[10];
  const float* cnn1_wih = (const float*)d_in[11];
  const float* cnn1_whh = (const float*)d_in[12];
  const float* cnn1_bih = (const float*)d_in[13];
  const float* cnn1_bhh = (const float*)d_in[14];
  const float* vq0_wih  = (const float*)d_in[15];
  const float* vq0_whh  = (const float*)d_in[16];
  const float* vq0_bih  = (const float*)d_in[17];
  const float* vq0_bhh  = (const float*)d_in[18];
  const float* vq1_wih  = (const float*)d_in[19];
  const float* vq1_whh  = (const float*)d_in[20];
  const float* vq1_bih  = (const float*)d_in[21];
  const float* vq1_bhh  = (const float*)d_in[22];
  const float* proj_w   = (const float*)d_in[23];
  const float* proj_b   = (const float*)d_in[24];
  const float* codebook = (const float*)d_in[25];

  float* out     = (float*)d_out;
  float* ws_f    = (float*)d_ws;
  int*   ws_hist = (int*)d_ws + 16;

  hipLaunchKernelGGL(zero_ws_kernel, dim3(1), dim3(64), 0, stream, ws_f, ws_hist);
  hipLaunchKernelGGL(fused_kernel, dim3(2*NBLK_STREAM), dim3(512), 0, stream,
                     x, conv_w, conv_b, bn_g, bn_b, bn_m, bn_v,
                     cnn0_wih, cnn0_whh, cnn0_bih, cnn0_bhh,
                     cnn1_wih, cnn1_whh, cnn1_bih, cnn1_bhh,
                     vq0_wih, vq0_whh, vq0_bih, vq0_bhh,
                     vq1_wih, vq1_whh, vq1_bih, vq1_bhh,
                     proj_w, proj_b, codebook, out, ws_f, ws_hist);
  hipLaunchKernelGGL(vq_finalize_kernel, dim3(1), dim3(64), 0, stream, ws_f, ws_hist, out);
}

// Round 5
// 1525.692 us; speedup vs baseline: 3.8222x; 1.1200x over previous
//
#include <hip/hip_runtime.h>
#include <math.h>
#include <stdint.h>

#define B_TOT 2048
#define SEQ   512
#define DIN   5
#define HID   64
#define EDIM  32
#define NEMB  64
#define BT    16
#define NBLK_STREAM 128
#define COMB  96
#define OUTC  (B_TOT*COMB)
#define GPAD  261

typedef __attribute__((ext_vector_type(8))) short short8;    // 8 bf16 = 4 VGPRs
typedef __attribute__((ext_vector_type(4))) float float4v;

__device__ __forceinline__ float fsig(float x){ return 1.0f/(1.0f + __expf(-x)); }
__device__ __forceinline__ float ftanh(float x){
  float xc = fminf(fmaxf(x, -15.f), 15.f);
  float e  = __expf(-2.f*xc);
  return (1.f - e) / (1.f + e);
}
__device__ __forceinline__ short f2bf(float f){        // RNE fp32 -> bf16
  uint32_t u = __float_as_uint(f);
  uint32_t r = u + 0x7FFFu + ((u >> 16) & 1u);
  return (short)(r >> 16);
}
__device__ __forceinline__ float bf2f(short h){
  return __uint_as_float(((uint32_t)(uint16_t)h) << 16);
}
__device__ __forceinline__ void f2bf2(float f, short& hi, short& lo){
  hi = f2bf(f);
  lo = f2bf(f - bf2f(hi));
}
#define MFMA(a,b,c) __builtin_amdgcn_mfma_f32_16x16x32_bf16((a),(b),(c),0,0,0)

// Fused dual-stream: blocks [0,128)=CNN, [128,256)=VQ. 512 thr = 8 waves.
// 2-barrier pipelined step: phase A = MFMA{G1(t), G0(t+1)}; phase B =
// act{L1(t), L0(t+1)} + conv y(t+2). Valid because L0gates(t+1) needs only
// h0(t) (and y(t+1)), not h1(t).
// Z invariant at top of iter t: Z0=[y/x(t+1); h0(t)], Z1=[h0(t); h1(t-1)].
__global__ __launch_bounds__(512)
__attribute__((amdgpu_waves_per_eu(2, 2)))
void fused_kernel(const float* __restrict__ xg,
                  const float* __restrict__ conv_w, const float* __restrict__ conv_b,
                  const float* __restrict__ bn_g, const float* __restrict__ bn_b,
                  const float* __restrict__ bn_m, const float* __restrict__ bn_v,
                  const float* __restrict__ cnn0_wih, const float* __restrict__ cnn0_whh,
                  const float* __restrict__ cnn0_bih, const float* __restrict__ cnn0_bhh,
                  const float* __restrict__ cnn1_wih, const float* __restrict__ cnn1_whh,
                  const float* __restrict__ cnn1_bih, const float* __restrict__ cnn1_bhh,
                  const float* __restrict__ vq0_wih, const float* __restrict__ vq0_whh,
                  const float* __restrict__ vq0_bih, const float* __restrict__ vq0_bhh,
                  const float* __restrict__ vq1_wih, const float* __restrict__ vq1_whh,
                  const float* __restrict__ vq1_bih, const float* __restrict__ vq1_bhh,
                  const float* __restrict__ proj_w, const float* __restrict__ proj_b,
                  const float* __restrict__ codebook,
                  float* __restrict__ out, float* __restrict__ ws_f,
                  int* __restrict__ ws_hist)
{
  __shared__ __align__(16) short Z0hi[3][4][BT][8], Z0lo[3][4][BT][8];  // K=96
  __shared__ __align__(16) short Z1hi[4][4][BT][8], Z1lo[4][4][BT][8];  // K=128
  __shared__ __align__(16) float Gbuf[2][BT][GPAD];   // [0]=G1(t), [1]=G0(t+1)
  __shared__ __align__(16) float hfin[BT][HID];
  __shared__ __align__(16) float pbuf[BT][EDIM];
  __shared__ float wcs[16][32];
  __shared__ float xwin[3][BT][DIN];

  const int tid  = threadIdx.x;
  const bool is_cnn = (blockIdx.x < NBLK_STREAM);
  const int b0   = (is_cnn ? blockIdx.x : blockIdx.x - NBLK_STREAM) * BT;
  const int w    = tid >> 6;
  const int lane = tid & 63;
  const int n16  = lane & 15;     // MFMA B/D col = batch
  const int quad = lane >> 4;

  const float* wih0 = is_cnn ? cnn0_wih : vq0_wih;
  const float* whh0 = is_cnn ? cnn0_whh : vq0_whh;
  const float* bih0 = is_cnn ? cnn0_bih : vq0_bih;
  const float* bhh0 = is_cnn ? cnn0_bhh : vq0_bhh;
  const float* wih1 = is_cnn ? cnn1_wih : vq1_wih;
  const float* whh1 = is_cnn ? cnn1_whh : vq1_whh;
  const float* bih1 = is_cnn ? cnn1_bih : vq1_bih;
  const float* bhh1 = is_cnn ? cnn1_bhh : vq1_bhh;

  // ---- static A-fragments (weights) bf16 hi/lo. A[m=lane&15][k=quad*8+j]
  short8 Ah0[2][3], Al0[2][3], Ah1[2][4], Al1[2][4];
#pragma unroll
  for (int T = 0; T < 2; ++T) {
    const int row = 16*(2*w + T) + n16;
#pragma unroll
    for (int kt = 0; kt < 3; ++kt) {
      short8 vh, vl;
#pragma unroll
      for (int j = 0; j < 8; ++j) {
        const int g = kt*32 + quad*8 + j;
        float wv;
        if (is_cnn) wv = (g < 32) ? wih0[row*32 + g] : whh0[row*64 + (g-32)];
        else        wv = (g < 5) ? wih0[row*5 + g] : (g < 32 ? 0.f : whh0[row*64 + (g-32)]);
        short hi, lo; f2bf2(wv, hi, lo); vh[j] = hi; vl[j] = lo;
      }
      Ah0[T][kt] = vh; Al0[T][kt] = vl;
    }
#pragma unroll
    for (int kt = 0; kt < 4; ++kt) {
      short8 vh, vl;
#pragma unroll
      for (int j = 0; j < 8; ++j) {
        const int g = kt*32 + quad*8 + j;
        float wv = (g < 64) ? wih1[row*64 + g] : whh1[row*64 + (g-64)];
        short hi, lo; f2bf2(wv, hi, lo); vh[j] = hi; vl[j] = lo;
      }
      Ah1[T][kt] = vh; Al1[T][kt] = vl;
    }
  }

  // act identity: units u = 8w + 2quad + {0,1}, batch n16
  const int uu0 = 8*w + 2*quad;
  float bb0[2][4], bb1[2][4];
#pragma unroll
  for (int g = 0; g < 4; ++g) {
    bb0[0][g] = bih0[uu0   + 64*g] + bhh0[uu0   + 64*g];
    bb0[1][g] = bih0[uu0+1 + 64*g] + bhh0[uu0+1 + 64*g];
    bb1[0][g] = bih1[uu0   + 64*g] + bhh1[uu0   + 64*g];
    bb1[1][g] = bih1[uu0+1 + 64*g] + bhh1[uu0+1 + 64*g];
  }

  // zero-init Z operands (pads stay zero)
  for (int i2 = tid; i2 < 3*4*BT*8/2; i2 += 512) { ((uint32_t*)Z0hi)[i2] = 0; ((uint32_t*)Z0lo)[i2] = 0; }
  for (int i2 = tid; i2 < 4*4*BT*8/2; i2 += 512) { ((uint32_t*)Z1hi)[i2] = 0; ((uint32_t*)Z1lo)[i2] = 0; }

  const int xn = tid / 5, xi = tid % 5;
  float xpref = 0.f;

  // ================= prologue =================
  if (is_cnn) {
    if (tid < 32) {
      float s = bn_g[tid] * rsqrtf(bn_v[tid] + 1e-5f);
#pragma unroll
      for (int i = 0; i < 5; ++i)
#pragma unroll
        for (int tau = 0; tau < 3; ++tau)
          wcs[tau*5 + i][tid] = conv_w[tid*15 + i*3 + tau] * s;
      wcs[15][tid] = (conv_b[tid] - bn_m[tid]) * s + bn_b[tid];
    }
    if (tid < 80) {
      xwin[0][xn][xi] = xg[((size_t)(b0+xn)*SEQ + 0)*DIN + xi];
      xwin[1][xn][xi] = xg[((size_t)(b0+xn)*SEQ + 1)*DIN + xi];
      xwin[2][xn][xi] = xg[((size_t)(b0+xn)*SEQ + 2)*DIN + xi];
    }
    __syncthreads();
    {   // conv y(0): taps x(-1)=0, x(0), x(1)
      const int cc = tid >> 4, cn = tid & 15;
      float s = wcs[15][cc];
#pragma unroll
      for (int i = 0; i < 5; ++i)
        s += wcs[5+i][cc]*xwin[0][cn][i] + wcs[10+i][cc]*xwin[1][cn][i];
      s = fmaxf(s, 0.f);
      short hi, lo; f2bf2(s, hi, lo);
      Z0hi[0][cc>>3][cn][cc&7] = hi; Z0lo[0][cc>>3][cn][cc&7] = lo;
    }
  } else {
    if (tid < 80) {   // x(0) into Z0 k<5
      float xv = xg[((size_t)(b0+xn)*SEQ + 0)*DIN + xi];
      short hi, lo; f2bf2(xv, hi, lo);
      Z0hi[0][0][xn][xi] = hi; Z0lo[0][0][xn][xi] = lo;
    }
  }
  __syncthreads();
  // MFMA G0(0) -> Gbuf[1]
  {
    float4v A00 = {0,0,0,0}, A01 = {0,0,0,0};
#pragma unroll
    for (int kt = 0; kt < 3; ++kt) {
      short8 bh = *(const short8*)&Z0hi[kt][quad][n16][0];
      short8 bl = *(const short8*)&Z0lo[kt][quad][n16][0];
      A00 = MFMA(Ah0[0][kt], bh, A00); A00 = MFMA(Ah0[0][kt], bl, A00); A00 = MFMA(Al0[0][kt], bh, A00);
      A01 = MFMA(Ah0[1][kt], bh, A01); A01 = MFMA(Ah0[1][kt], bl, A01); A01 = MFMA(Al0[1][kt], bh, A01);
    }
#pragma unroll
    for (int r = 0; r < 4; ++r) {
      Gbuf[1][n16][16*(2*w+0) + 4*quad + r] = A00[r];
      Gbuf[1][n16][16*(2*w+1) + 4*quad + r] = A01[r];
    }
  }
  __syncthreads();

  float c0[2] = {0,0}, c1[2] = {0,0}, h1v[2] = {0,0};
  // act L0(0) -> h0(0); stage next x/y into Z0
  {
#pragma unroll
    for (int jj = 0; jj < 2; ++jj) {
      const int u = uu0 + jj;
      float g0 = Gbuf[1][n16][u]       + bb0[jj][0];
      float g1 = Gbuf[1][n16][u + 64]  + bb0[jj][1];
      float g2 = Gbuf[1][n16][u + 128] + bb0[jj][2];
      float g3 = Gbuf[1][n16][u + 192] + bb0[jj][3];
      c0[jj] = fsig(g1)*c0[jj] + fsig(g0)*ftanh(g2);
      float h0 = fsig(g3)*ftanh(c0[jj]);
      short hi, lo; f2bf2(h0, hi, lo);
      Z1hi[u>>5][(u>>3)&3][n16][u&7] = hi;     // Z1 k=u
      Z1lo[u>>5][(u>>3)&3][n16][u&7] = lo;
      const int k2 = 32 + u;                    // Z0 k=32+u
      Z0hi[k2>>5][(k2>>3)&3][n16][k2&7] = hi;
      Z0lo[k2>>5][(k2>>3)&3][n16][k2&7] = lo;
    }
    if (is_cnn) {
      const int cc = tid >> 4, cn = tid & 15;   // conv y(1): x(0),x(1),x(2)
      float s = wcs[15][cc];
#pragma unroll
      for (int i = 0; i < 5; ++i)
        s += wcs[i][cc]*xwin[0][cn][i] + wcs[5+i][cc]*xwin[1][cn][i]
           + wcs[10+i][cc]*xwin[2][cn][i];
      s = fmaxf(s, 0.f);
      short hi, lo; f2bf2(s, hi, lo);
      Z0hi[0][cc>>3][cn][cc&7] = hi; Z0lo[0][cc>>3][cn][cc&7] = lo;
      if (tid < 80) xpref = xg[((size_t)(b0+xn)*SEQ + 3)*DIN + xi];     // x(3)
    } else {
      if (tid < 80) {                            // x(1) into Z0 k<5
        float xv = xg[((size_t)(b0+xn)*SEQ + 1)*DIN + xi];
        short hi, lo; f2bf2(xv, hi, lo);
        Z0hi[0][0][xn][xi] = hi; Z0lo[0][0][xn][xi] = lo;
        xpref = xg[((size_t)(b0+xn)*SEQ + 2)*DIN + xi];                 // x(2)
      }
    }
  }
  __syncthreads();

  int sp = 1, scu = 2, snx = 0;   // cnn: slots x(t+1), x(t+2), x(t+3)-incoming

  // ================= main loop: 2 barriers/step =================
  for (int t = 0; t < SEQ; ++t) {
    // ---- phase A: commit x(t+3) to xwin (cnn) + MFMA G1(t), G0(t+1)
    if (is_cnn && tid < 80) xwin[snx][xn][xi] = xpref;
    {
      float4v A10 = {0,0,0,0}, A11 = {0,0,0,0}, A00 = {0,0,0,0}, A01 = {0,0,0,0};
#pragma unroll
      for (int kt = 0; kt < 4; ++kt) {
        short8 bh = *(const short8*)&Z1hi[kt][quad][n16][0];
        short8 bl = *(const short8*)&Z1lo[kt][quad][n16][0];
        A10 = MFMA(Ah1[0][kt], bh, A10); A10 = MFMA(Ah1[0][kt], bl, A10); A10 = MFMA(Al1[0][kt], bh, A10);
        A11 = MFMA(Ah1[1][kt], bh, A11); A11 = MFMA(Ah1[1][kt], bl, A11); A11 = MFMA(Al1[1][kt], bh, A11);
      }
#pragma unroll
      for (int kt = 0; kt < 3; ++kt) {
        short8 bh = *(const short8*)&Z0hi[kt][quad][n16][0];
        short8 bl = *(const short8*)&Z0lo[kt][quad][n16][0];
        A00 = MFMA(Ah0[0][kt], bh, A00); A00 = MFMA(Ah0[0][kt], bl, A00); A00 = MFMA(Al0[0][kt], bh, A00);
        A01 = MFMA(Ah0[1][kt], bh, A01); A01 = MFMA(Ah0[1][kt], bl, A01); A01 = MFMA(Al0[1][kt], bh, A01);
      }
#pragma unroll
      for (int r = 0; r < 4; ++r) {
        Gbuf[0][n16][16*(2*w+0) + 4*quad + r] = A10[r];
        Gbuf[0][n16][16*(2*w+1) + 4*quad + r] = A11[r];
        Gbuf[1][n16][16*(2*w+0) + 4*quad + r] = A00[r];
        Gbuf[1][n16][16*(2*w+1) + 4*quad + r] = A01[r];
      }
    }
    __syncthreads();  // A -> B

    // ---- phase B: L1 act(t), L0 act(t+1), conv y(t+2) / x(t+2) stage
#pragma unroll
    for (int jj = 0; jj < 2; ++jj) {   // L1 act
      const int u = uu0 + jj;
      float g0 = Gbuf[0][n16][u]       + bb1[jj][0];
      float g1 = Gbuf[0][n16][u + 64]  + bb1[jj][1];
      float g2 = Gbuf[0][n16][u + 128] + bb1[jj][2];
      float g3 = Gbuf[0][n16][u + 192] + bb1[jj][3];
      c1[jj] = fsig(g1)*c1[jj] + fsig(g0)*ftanh(g2);
      float h1 = fsig(g3)*ftanh(c1[jj]);
      short hi, lo; f2bf2(h1, hi, lo);
      const int k3 = 64 + u;
      Z1hi[k3>>5][(k3>>3)&3][n16][k3&7] = hi;
      Z1lo[k3>>5][(k3>>3)&3][n16][k3&7] = lo;
      if (is_cnn) h1v[jj] = h1;
      else if (t == SEQ-1) hfin[n16][u] = h1;
    }
#pragma unroll
    for (int jj = 0; jj < 2; ++jj) {   // L0 act (step t+1)
      const int u = uu0 + jj;
      float g0 = Gbuf[1][n16][u]       + bb0[jj][0];
      float g1 = Gbuf[1][n16][u + 64]  + bb0[jj][1];
      float g2 = Gbuf[1][n16][u + 128] + bb0[jj][2];
      float g3 = Gbuf[1][n16][u + 192] + bb0[jj][3];
      c0[jj] = fsig(g1)*c0[jj] + fsig(g0)*ftanh(g2);
      float h0 = fsig(g3)*ftanh(c0[jj]);
      short hi, lo; f2bf2(h0, hi, lo);
      Z1hi[u>>5][(u>>3)&3][n16][u&7] = hi;
      Z1lo[u>>5][(u>>3)&3][n16][u&7] = lo;
      const int k2 = 32 + u;
      Z0hi[k2>>5][(k2>>3)&3][n16][k2&7] = hi;
      Z0lo[k2>>5][(k2>>3)&3][n16][k2&7] = lo;
    }
    if (is_cnn) {   // conv y(t+2): taps x(t+1),x(t+2),x(t+3)
      const int cc = tid >> 4, cn = tid & 15;
      float s = wcs[15][cc];
#pragma unroll
      for (int i = 0; i < 5; ++i)
        s += wcs[i][cc]*xwin[sp][cn][i] + wcs[5+i][cc]*xwin[scu][cn][i]
           + wcs[10+i][cc]*xwin[snx][cn][i];
      s = fmaxf(s, 0.f);
      short hi, lo; f2bf2(s, hi, lo);
      Z0hi[0][cc>>3][cn][cc&7] = hi; Z0lo[0][cc>>3][cn][cc&7] = lo;
      if (tid < 80) {
        const int tq = t + 4;
        xpref = (tq < SEQ) ? xg[((size_t)(b0+xn)*SEQ + tq)*DIN + xi] : 0.f;
      }
    } else {
      if (tid < 80) {   // x(t+2) into Z0 k<5
        short hi, lo; f2bf2(xpref, hi, lo);
        Z0hi[0][0][xn][xi] = hi; Z0lo[0][0][xn][xi] = lo;
        const int tq = t + 3;
        xpref = (tq < SEQ) ? xg[((size_t)(b0+xn)*SEQ + tq)*DIN + xi] : 0.f;
      }
    }
    { int tmp = sp; sp = scu; scu = snx; snx = tmp; }
    __syncthreads();  // B -> A(t+1)
  }

  // ================= epilogue =================
  if (is_cnn) {
    const size_t gb = (size_t)(b0 + n16);
    out[gb*COMB + uu0]          = h1v[0];
    out[OUTC + gb*COMB + uu0]   = h1v[0];
    out[gb*COMB + uu0+1]        = h1v[1];
    out[OUTC + gb*COMB + uu0+1] = h1v[1];
  } else {
    {  // projection: vq_proj[16][32]
      const int pn = tid >> 5, pe = tid & 31;
      float s = proj_b[pe];
      const float* pw = proj_w + pe*HID;
#pragma unroll
      for (int k = 0; k < HID; ++k) s += hfin[pn][k] * pw[k];
      pbuf[pn][pe] = s;
    }
    __syncthreads();
    // argmin: wave w handles batches 2w, 2w+1; lane = code index
#pragma unroll
    for (int rep = 0; rep < 2; ++rep) {
      const int bb = 2*w + rep;
      const int nn = lane;
      const float* cbn = codebook + nn*EDIM;
      float d = 0.f;
#pragma unroll
      for (int k = 0; k < EDIM; ++k) { float df = pbuf[bb][k] - cbn[k]; d += df*df; }
      int bi = nn;
#pragma unroll
      for (int off = 32; off > 0; off >>= 1) {
        float od = __shfl_down(d, off, 64);
        int   oi = __shfl_down(bi, off, 64);
        if (od < d || (od == d && oi < bi)) { d = od; bi = oi; }
      }
      bi = __shfl(bi, 0, 64);
      float lv = 0.f;
      if (nn < EDIM) {
        float q = codebook[bi*EDIM + nn];
        const size_t gb = (size_t)(b0 + bb);
        out[gb*COMB + HID + nn]        = q;
        out[OUTC + gb*COMB + HID + nn] = q;
        float df = q - pbuf[bb][nn];
        lv = df*df;
      }
#pragma unroll
      for (int off = 32; off > 0; off >>= 1) lv += __shfl_down(lv, off, 64);
      if (nn == 0) { atomicAdd(ws_f, lv); atomicAdd(&ws_hist[bi], 1); }
    }
  }
}

// ===================== scalars =====================
__global__ void zero_ws_kernel(float* ws_f, int* ws_hist) {
  const int t = threadIdx.x;
  if (t == 0) ws_f[0] = 0.f;
  if (t < NEMB) ws_hist[t] = 0;
}

__global__ void vq_finalize_kernel(const float* __restrict__ ws_f,
                                   const int* __restrict__ ws_hist,
                                   float* __restrict__ out) {
  const int t = threadIdx.x;  // 64 threads = 1 wave
  float p = (float)ws_hist[t] * (1.0f / (float)B_TOT);
  float e = -p * logf(p + 1e-10f);
#pragma unroll
  for (int off = 32; off > 0; off >>= 1) e += __shfl_down(e, off, 64);
  if (t == 0) {
    float mse = ws_f[0] * (1.0f / (float)(B_TOT * EDIM));
    out[2*OUTC + 0] = mse * 1.01f;   // q_loss + 0.01*e_loss (identical fwd)
    out[2*OUTC + 1] = expf(e);       // perplexity
  }
}

extern "C" void kernel_launch(void* const* d_in, const int* in_sizes, int n_in,
                              void* d_out, int out_size, void* d_ws, size_t ws_size,
                              hipStream_t stream) {
  const float* x        = (const float*)d_in[0];
  const float* conv_w   = (const float*)d_in[1];
  const float* conv_b   = (const float*)d_in[2];
  const float* bn_g     = (const float*)d_in[3];
  const float* bn_b     = (const float*)d_in[4];
  const float* bn_m     = (const float*)d_in[5];
  const float* bn_v     = (const float*)d_in[6];
  const float* cnn0_wih = (const float*)d_in[7];
  const float* cnn0_whh = (const float*)d_in[8];
  const float* cnn0_bih = (const float*)d_in[9];
  const float* cnn0_bhh = (const float*)d_in[10];
  const float* cnn1_wih = (const float*)d_in[11];
  const float* cnn1_whh = (const float*)d_in[12];
  const float* cnn1_bih = (const float*)d_in[13];
  const float* cnn1_bhh = (const float*)d_in[14];
  const float* vq0_wih  = (const float*)d_in[15];
  const float* vq0_whh  = (const float*)d_in[16];
  const float* vq0_bih  = (const float*)d_in[17];
  const float* vq0_bhh  = (const float*)d_in[18];
  const float* vq1_wih  = (const float*)d_in[19];
  const float* vq1_whh  = (const float*)d_in[20];
  const float* vq1_bih  = (const float*)d_in[21];
  const float* vq1_bhh  = (const float*)d_in[22];
  const float* proj_w   = (const float*)d_in[23];
  const float* proj_b   = (const float*)d_in[24];
  const float* codebook = (const float*)d_in[25];

  float* out     = (float*)d_out;
  float* ws_f    = (float*)d_ws;
  int*   ws_hist = (int*)d_ws + 16;

  hipLaunchKernelGGL(zero_ws_kernel, dim3(1), dim3(64), 0, stream, ws_f, ws_hist);
  hipLaunchKernelGGL(fused_kernel, dim3(2*NBLK_STREAM), dim3(512), 0, stream,
                     x, conv_w, conv_b, bn_g, bn_b, bn_m, bn_v,
                     cnn0_wih, cnn0_whh, cnn0_bih, cnn0_bhh,
                     cnn1_wih, cnn1_whh, cnn1_bih, cnn1_bhh,
                     vq0_wih, vq0_whh, vq0_bih, vq0_bhh,
                     vq1_wih, vq1_whh, vq1_bih, vq1_bhh,
                     proj_w, proj_b, codebook, out, ws_f, ws_hist);
  hipLaunchKernelGGL(vq_finalize_kernel, dim3(1), dim3(64), 0, stream, ws_f, ws_hist, out);
}

// Round 6
// 1182.590 us; speedup vs baseline: 4.9312x; 1.2901x over previous
//
#include <hip/hip_runtime.h>
#include <math.h>
#include <stdint.h>

#define B_TOT 2048
#define SEQ   512
#define DIN   5
#define HID   64
#define EDIM  32
#define NEMB  64
#define BT    16
#define NBLK_STREAM 128
#define COMB  96
#define OUTC  (B_TOT*COMB)

typedef __attribute__((ext_vector_type(8))) short short8;    // 8 bf16 = 4 VGPRs
typedef __attribute__((ext_vector_type(4))) float float4v;

__device__ __forceinline__ float fsig(float x){ return 1.0f/(1.0f + __expf(-x)); }
__device__ __forceinline__ float ftanh(float x){
  float xc = fminf(fmaxf(x, -15.f), 15.f);
  float e  = __expf(-2.f*xc);
  return (1.f - e) / (1.f + e);
}
__device__ __forceinline__ short f2bf(float f){        // RNE fp32 -> bf16
  uint32_t u = __float_as_uint(f);
  uint32_t r = u + 0x7FFFu + ((u >> 16) & 1u);
  return (short)(r >> 16);
}
__device__ __forceinline__ float bf2f(short h){
  return __uint_as_float(((uint32_t)(uint16_t)h) << 16);
}
__device__ __forceinline__ void f2bf2(float f, short& hi, short& lo){
  hi = f2bf(f);
  lo = f2bf(f - bf2f(hi));
}
#define MFMA(a,b,c) __builtin_amdgcn_mfma_f32_16x16x32_bf16((a),(b),(c),0,0,0)

// Z layout [k>>3][n][k&7] shorts: flat idx = (k>>3)*(BT*8) + n*8 + (k&7)
__device__ __forceinline__ void zst(short* Zh, short* Zl, int k, int n, short hi, short lo){
  const int idx = (k >> 3)*(BT*8) + n*8 + (k & 7);
  Zh[idx] = hi; Zl[idx] = lo;
}

// Fused dual-stream: blocks [0,128)=CNN, [128,256)=VQ. 1024 thr = 16 waves.
// Wave w owns gate-row tile w with PERMUTED rows: tile row m <-> orig row
// 64*(m&3) + 4*w + (m>>2). Then D-frag lane(n16,quad) reg r = gate r of unit
// u=4w+quad, batch n16 -> LSTM act is fully in-register (no G round-trip).
// 2 barriers/step: A = MFMA{G1(t),G0(t+1)}; B = in-reg act + Z/conv writes.
__global__ __launch_bounds__(1024)
__attribute__((amdgpu_waves_per_eu(4, 4)))
void fused_kernel(const float* __restrict__ xg,
                  const float* __restrict__ conv_w, const float* __restrict__ conv_b,
                  const float* __restrict__ bn_g, const float* __restrict__ bn_b,
                  const float* __restrict__ bn_m, const float* __restrict__ bn_v,
                  const float* __restrict__ cnn0_wih, const float* __restrict__ cnn0_whh,
                  const float* __restrict__ cnn0_bih, const float* __restrict__ cnn0_bhh,
                  const float* __restrict__ cnn1_wih, const float* __restrict__ cnn1_whh,
                  const float* __restrict__ cnn1_bih, const float* __restrict__ cnn1_bhh,
                  const float* __restrict__ vq0_wih, const float* __restrict__ vq0_whh,
                  const float* __restrict__ vq0_bih, const float* __restrict__ vq0_bhh,
                  const float* __restrict__ vq1_wih, const float* __restrict__ vq1_whh,
                  const float* __restrict__ vq1_bih, const float* __restrict__ vq1_bhh,
                  const float* __restrict__ proj_w, const float* __restrict__ proj_b,
                  const float* __restrict__ codebook,
                  float* __restrict__ out, float* __restrict__ ws_f,
                  int* __restrict__ ws_hist)
{
  __shared__ __align__(16) short Z0hi[3][4][BT][8], Z0lo[3][4][BT][8];  // K=96
  __shared__ __align__(16) short Z1hi[4][4][BT][8], Z1lo[4][4][BT][8];  // K=128
  __shared__ __align__(16) float hfin[BT][HID];
  __shared__ __align__(16) float pbuf[BT][EDIM];
  __shared__ float wcs[16][32];
  __shared__ float xwin[3][BT][DIN];

  const int tid  = threadIdx.x;
  const bool is_cnn = (blockIdx.x < NBLK_STREAM);
  const int b0   = (is_cnn ? blockIdx.x : blockIdx.x - NBLK_STREAM) * BT;
  const int w    = tid >> 6;      // wave = M-tile
  const int lane = tid & 63;
  const int n16  = lane & 15;     // batch (B/D col)
  const int quad = lane >> 4;
  const int u    = 4*w + quad;    // unit owned by this lane

  const float* wih0 = is_cnn ? cnn0_wih : vq0_wih;
  const float* whh0 = is_cnn ? cnn0_whh : vq0_whh;
  const float* bih0 = is_cnn ? cnn0_bih : vq0_bih;
  const float* bhh0 = is_cnn ? cnn0_bhh : vq0_bhh;
  const float* wih1 = is_cnn ? cnn1_wih : vq1_wih;
  const float* whh1 = is_cnn ? cnn1_whh : vq1_whh;
  const float* bih1 = is_cnn ? cnn1_bih : vq1_bih;
  const float* bhh1 = is_cnn ? cnn1_bhh : vq1_bhh;

  // ---- A-frags (bf16 hi/lo), permuted rows. A[m=lane&15][k=quad*8+j]
  const int orow = 64*(n16 & 3) + 4*w + (n16 >> 2);
  short8 Ah0[3], Al0[3], Ah1[4], Al1[4];
#pragma unroll
  for (int kt = 0; kt < 3; ++kt) {
    short8 vh, vl;
#pragma unroll
    for (int j = 0; j < 8; ++j) {
      const int g = kt*32 + quad*8 + j;
      float wv;
      if (is_cnn) wv = (g < 32) ? wih0[orow*32 + g] : whh0[orow*64 + (g-32)];
      else        wv = (g < 5) ? wih0[orow*5 + g] : (g < 32 ? 0.f : whh0[orow*64 + (g-32)]);
      short hi, lo; f2bf2(wv, hi, lo); vh[j] = hi; vl[j] = lo;
    }
    Ah0[kt] = vh; Al0[kt] = vl;
  }
#pragma unroll
  for (int kt = 0; kt < 4; ++kt) {
    short8 vh, vl;
#pragma unroll
    for (int j = 0; j < 8; ++j) {
      const int g = kt*32 + quad*8 + j;
      float wv = (g < 64) ? wih1[orow*64 + g] : whh1[orow*64 + (g-64)];
      short hi, lo; f2bf2(wv, hi, lo); vh[j] = hi; vl[j] = lo;
    }
    Ah1[kt] = vh; Al1[kt] = vl;
  }

  // biases: gate r of unit u
  float bb0[4], bb1[4];
#pragma unroll
  for (int r = 0; r < 4; ++r) {
    bb0[r] = bih0[64*r + u] + bhh0[64*r + u];
    bb1[r] = bih1[64*r + u] + bhh1[64*r + u];
  }

  // zero Z operands (pads stay zero; h(-1)=0)
  for (int i2 = tid; i2 < 3*4*BT*8/2; i2 += 1024) { ((uint32_t*)Z0hi)[i2] = 0; ((uint32_t*)Z0lo)[i2] = 0; }
  for (int i2 = tid; i2 < 4*4*BT*8/2; i2 += 1024) { ((uint32_t*)Z1hi)[i2] = 0; ((uint32_t*)Z1lo)[i2] = 0; }

  const int xn = tid / 5, xi = tid % 5;
  float xpref = 0.f;

  // ================= prologue =================
  if (is_cnn) {
    if (tid < 32) {
      float s = bn_g[tid] * rsqrtf(bn_v[tid] + 1e-5f);
#pragma unroll
      for (int i = 0; i < 5; ++i)
#pragma unroll
        for (int tau = 0; tau < 3; ++tau)
          wcs[tau*5 + i][tid] = conv_w[tid*15 + i*3 + tau] * s;
      wcs[15][tid] = (conv_b[tid] - bn_m[tid]) * s + bn_b[tid];
    }
    if (tid < 80) {
      xwin[0][xn][xi] = xg[((size_t)(b0+xn)*SEQ + 0)*DIN + xi];
      xwin[1][xn][xi] = xg[((size_t)(b0+xn)*SEQ + 1)*DIN + xi];
      xwin[2][xn][xi] = xg[((size_t)(b0+xn)*SEQ + 2)*DIN + xi];
    }
    __syncthreads();
    if (tid < 512) {   // conv y(0): taps x(-1)=0, x(0), x(1)
      const int cc = tid >> 4, cn = tid & 15;
      float s = wcs[15][cc];
#pragma unroll
      for (int i = 0; i < 5; ++i)
        s += wcs[5+i][cc]*xwin[0][cn][i] + wcs[10+i][cc]*xwin[1][cn][i];
      s = fmaxf(s, 0.f);
      short hi, lo; f2bf2(s, hi, lo);
      zst((short*)Z0hi, (short*)Z0lo, cc, cn, hi, lo);
    }
  } else {
    if (tid < 80) {   // x(0) into Z0 k<5
      float xv = xg[((size_t)(b0+xn)*SEQ + 0)*DIN + xi];
      short hi, lo; f2bf2(xv, hi, lo);
      zst((short*)Z0hi, (short*)Z0lo, xi, xn, hi, lo);
    }
  }
  __syncthreads();

  float c0 = 0.f, c1 = 0.f, h1v = 0.f;
  // MFMA G0(0)
  {
    float4v A0 = {0,0,0,0};
#pragma unroll
    for (int kt = 0; kt < 3; ++kt) {
      short8 bh = *(const short8*)&Z0hi[kt][quad][n16][0];
      short8 bl = *(const short8*)&Z0lo[kt][quad][n16][0];
      A0 = MFMA(Ah0[kt], bh, A0); A0 = MFMA(Ah0[kt], bl, A0); A0 = MFMA(Al0[kt], bh, A0);
    }
    __syncthreads();   // all reads done before act writes
    // act L0(0) in-register: reg r = gate r of (u, n16)
    float gi = A0[0]+bb0[0], gf = A0[1]+bb0[1], gg = A0[2]+bb0[2], go = A0[3]+bb0[3];
    c0 = fsig(gf)*c0 + fsig(gi)*ftanh(gg);
    float h0 = fsig(go)*ftanh(c0);
    short hi, lo; f2bf2(h0, hi, lo);
    zst((short*)Z1hi, (short*)Z1lo, u,      n16, hi, lo);
    zst((short*)Z0hi, (short*)Z0lo, 32 + u, n16, hi, lo);
  }
  // stage y(1)/x(1), prefetch
  if (is_cnn) {
    if (tid < 512) {   // conv y(1): x(0),x(1),x(2)
      const int cc = tid >> 4, cn = tid & 15;
      float s = wcs[15][cc];
#pragma unroll
      for (int i = 0; i < 5; ++i)
        s += wcs[i][cc]*xwin[0][cn][i] + wcs[5+i][cc]*xwin[1][cn][i]
           + wcs[10+i][cc]*xwin[2][cn][i];
      s = fmaxf(s, 0.f);
      short hi, lo; f2bf2(s, hi, lo);
      zst((short*)Z0hi, (short*)Z0lo, cc, cn, hi, lo);
    }
    if (tid < 80) xpref = xg[((size_t)(b0+xn)*SEQ + 3)*DIN + xi];   // x(3)
  } else {
    if (tid < 80) {    // x(1) into Z0 k<5
      float xv = xg[((size_t)(b0+xn)*SEQ + 1)*DIN + xi];
      short hi, lo; f2bf2(xv, hi, lo);
      zst((short*)Z0hi, (short*)Z0lo, xi, xn, hi, lo);
      xpref = xg[((size_t)(b0+xn)*SEQ + 2)*DIN + xi];               // x(2)
    }
  }
  __syncthreads();

  int sp = 1, scu = 2, snx = 0;   // cnn xwin slots: x(t+1), x(t+2), x(t+3)-incoming

  // ================= main loop: 2 barriers/step =================
  for (int t = 0; t < SEQ; ++t) {
    // ---- phase A: commit x(t+3) (cnn) + MFMA G1(t), G0(t+1)
    if (is_cnn && tid < 80) xwin[snx][xn][xi] = xpref;
    float4v A1 = {0,0,0,0}, A0 = {0,0,0,0};
#pragma unroll
    for (int kt = 0; kt < 4; ++kt) {
      short8 bh = *(const short8*)&Z1hi[kt][quad][n16][0];
      short8 bl = *(const short8*)&Z1lo[kt][quad][n16][0];
      A1 = MFMA(Ah1[kt], bh, A1); A1 = MFMA(Ah1[kt], bl, A1); A1 = MFMA(Al1[kt], bh, A1);
    }
#pragma unroll
    for (int kt = 0; kt < 3; ++kt) {
      short8 bh = *(const short8*)&Z0hi[kt][quad][n16][0];
      short8 bl = *(const short8*)&Z0lo[kt][quad][n16][0];
      A0 = MFMA(Ah0[kt], bh, A0); A0 = MFMA(Ah0[kt], bl, A0); A0 = MFMA(Al0[kt], bh, A0);
    }
    __syncthreads();  // A -> B (Z reads complete)

    // ---- phase B: in-register acts + Z writes + conv/x staging
    {  // L1 act(t)
      float gi = A1[0]+bb1[0], gf = A1[1]+bb1[1], gg = A1[2]+bb1[2], go = A1[3]+bb1[3];
      c1 = fsig(gf)*c1 + fsig(gi)*ftanh(gg);
      float h1 = fsig(go)*ftanh(c1);
      short hi, lo; f2bf2(h1, hi, lo);
      zst((short*)Z1hi, (short*)Z1lo, 64 + u, n16, hi, lo);
      if (is_cnn) h1v = h1;
      else if (t == SEQ-1) hfin[n16][u] = h1;
    }
    {  // L0 act(t+1)
      float gi = A0[0]+bb0[0], gf = A0[1]+bb0[1], gg = A0[2]+bb0[2], go = A0[3]+bb0[3];
      c0 = fsig(gf)*c0 + fsig(gi)*ftanh(gg);
      float h0 = fsig(go)*ftanh(c0);
      short hi, lo; f2bf2(h0, hi, lo);
      zst((short*)Z1hi, (short*)Z1lo, u,      n16, hi, lo);
      zst((short*)Z0hi, (short*)Z0lo, 32 + u, n16, hi, lo);
    }
    if (is_cnn) {      // conv y(t+2): x(t+1),x(t+2),x(t+3)
      if (tid < 512) {
        const int cc = tid >> 4, cn = tid & 15;
        float s = wcs[15][cc];
#pragma unroll
        for (int i = 0; i < 5; ++i)
          s += wcs[i][cc]*xwin[sp][cn][i] + wcs[5+i][cc]*xwin[scu][cn][i]
             + wcs[10+i][cc]*xwin[snx][cn][i];
        s = fmaxf(s, 0.f);
        short hi, lo; f2bf2(s, hi, lo);
        zst((short*)Z0hi, (short*)Z0lo, cc, cn, hi, lo);
      }
      if (tid < 80) {
        const int tq = t + 4;
        xpref = (tq < SEQ) ? xg[((size_t)(b0+xn)*SEQ + tq)*DIN + xi] : 0.f;
      }
    } else {
      if (tid < 80) {  // x(t+2) into Z0 k<5
        short hi, lo; f2bf2(xpref, hi, lo);
        zst((short*)Z0hi, (short*)Z0lo, xi, xn, hi, lo);
        const int tq = t + 3;
        xpref = (tq < SEQ) ? xg[((size_t)(b0+xn)*SEQ + tq)*DIN + xi] : 0.f;
      }
    }
    { int tmp = sp; sp = scu; scu = snx; snx = tmp; }
    __syncthreads();  // B -> A(t+1)
  }

  // ================= epilogue =================
  if (is_cnn) {
    const size_t gb = (size_t)(b0 + n16);
    out[gb*COMB + u]        = h1v;
    out[OUTC + gb*COMB + u] = h1v;
  } else {
    if (tid < 512) {  // projection: vq_proj[16][32]
      const int pn = tid >> 5, pe = tid & 31;
      float s = proj_b[pe];
      const float* pw = proj_w + pe*HID;
#pragma unroll
      for (int k = 0; k < HID; ++k) s += hfin[pn][k] * pw[k];
      pbuf[pn][pe] = s;
    }
    __syncthreads();
    // argmin: wave w handles batch w (16 waves = 16 batches), lane = code idx
    {
      const int bb = w;
      const int nn = lane;
      const float* cbn = codebook + nn*EDIM;
      float d = 0.f;
#pragma unroll
      for (int k = 0; k < EDIM; ++k) { float df = pbuf[bb][k] - cbn[k]; d += df*df; }
      int bi = nn;
#pragma unroll
      for (int off = 32; off > 0; off >>= 1) {
        float od = __shfl_down(d, off, 64);
        int   oi = __shfl_down(bi, off, 64);
        if (od < d || (od == d && oi < bi)) { d = od; bi = oi; }
      }
      bi = __shfl(bi, 0, 64);
      float lv = 0.f;
      if (nn < EDIM) {
        float q = codebook[bi*EDIM + nn];
        const size_t gb = (size_t)(b0 + bb);
        out[gb*COMB + HID + nn]        = q;
        out[OUTC + gb*COMB + HID + nn] = q;
        float df = q - pbuf[bb][nn];
        lv = df*df;
      }
#pragma unroll
      for (int off = 32; off > 0; off >>= 1) lv += __shfl_down(lv, off, 64);
      if (nn == 0) { atomicAdd(ws_f, lv); atomicAdd(&ws_hist[bi], 1); }
    }
  }
}

// ===================== scalars =====================
__global__ void zero_ws_kernel(float* ws_f, int* ws_hist) {
  const int t = threadIdx.x;
  if (t == 0) ws_f[0] = 0.f;
  if (t < NEMB) ws_hist[t] = 0;
}

__global__ void vq_finalize_kernel(const float* __restrict__ ws_f,
                                   const int* __restrict__ ws_hist,
                                   float* __restrict__ out) {
  const int t = threadIdx.x;  // 64 threads = 1 wave
  float p = (float)ws_hist[t] * (1.0f / (float)B_TOT);
  float e = -p * logf(p + 1e-10f);
#pragma unroll
  for (int off = 32; off > 0; off >>= 1) e += __shfl_down(e, off, 64);
  if (t == 0) {
    float mse = ws_f[0] * (1.0f / (float)(B_TOT * EDIM));
    out[2*OUTC + 0] = mse * 1.01f;   // q_loss + 0.01*e_loss (identical fwd)
    out[2*OUTC + 1] = expf(e);       // perplexity
  }
}

extern "C" void kernel_launch(void* const* d_in, const int* in_sizes, int n_in,
                              void* d_out, int out_size, void* d_ws, size_t ws_size,
                              hipStream_t stream) {
  const float* x        = (const float*)d_in[0];
  const float* conv_w   = (const float*)d_in[1];
  const float* conv_b   = (const float*)d_in[2];
  const float* bn_g     = (const float*)d_in[3];
  const float* bn_b     = (const float*)d_in[4];
  const float* bn_m     = (const float*)d_in[5];
  const float* bn_v     = (const float*)d_in[6];
  const float* cnn0_wih = (const float*)d_in[7];
  const float* cnn0_whh = (const float*)d_in[8];
  const float* cnn0_bih = (const float*)d_in[9];
  const float* cnn0_bhh = (const float*)d_in[10];
  const float* cnn1_wih = (const float*)d_in[11];
  const float* cnn1_whh = (const float*)d_in[12];
  const float* cnn1_bih = (const float*)d_in[13];
  const float* cnn1_bhh = (const float*)d_in[14];
  const float* vq0_wih  = (const float*)d_in[15];
  const float* vq0_whh  = (const float*)d_in[16];
  const float* vq0_bih  = (const float*)d_in[17];
  const float* vq0_bhh  = (const float*)d_in[18];
  const float* vq1_wih  = (const float*)d_in[19];
  const float* vq1_whh  = (const float*)d_in[20];
  const float* vq1_bih  = (const float*)d_in[21];
  const float* vq1_bhh  = (const float*)d_in[22];
  const float* proj_w   = (const float*)d_in[23];
  const float* proj_b   = (const float*)d_in[24];
  const float* codebook = (const float*)d_in[25];

  float* out     = (float*)d_out;
  float* ws_f    = (float*)d_ws;
  int*   ws_hist = (int*)d_ws + 16;

  hipLaunchKernelGGL(zero_ws_kernel, dim3(1), dim3(64), 0, stream, ws_f, ws_hist);
  hipLaunchKernelGGL(fused_kernel, dim3(2*NBLK_STREAM), dim3(1024), 0, stream,
                     x, conv_w, conv_b, bn_g, bn_b, bn_m, bn_v,
                     cnn0_wih, cnn0_whh, cnn0_bih, cnn0_bhh,
                     cnn1_wih, cnn1_whh, cnn1_bih, cnn1_bhh,
                     vq0_wih, vq0_whh, vq0_bih, vq0_bhh,
                     vq1_wih, vq1_whh, vq1_bih, vq1_bhh,
                     proj_w, proj_b, codebook, out, ws_f, ws_hist);
  hipLaunchKernelGGL(vq_finalize_kernel, dim3(1), dim3(64), 0, stream, ws_f, ws_hist, out);
}

// Round 7
// 1062.946 us; speedup vs baseline: 5.4862x; 1.1126x over previous
//
#include <hip/hip_runtime.h>
#include <math.h>
#include <stdint.h>

#define B_TOT 2048
#define SEQ   512
#define DIN   5
#define HID   64
#define EDIM  32
#define NEMB  64
#define BT    16
#define NBLK_STREAM 128
#define COMB  96
#define OUTC  (B_TOT*COMB)

typedef __attribute__((ext_vector_type(8))) _Float16 half8;  // 8 fp16 = 4 VGPRs
typedef __attribute__((ext_vector_type(4))) float float4v;

__device__ __forceinline__ float fsig(float x){ return 1.0f/(1.0f + __expf(-x)); }
__device__ __forceinline__ float ftanh(float x){
  float xc = fminf(fmaxf(x, -15.f), 15.f);
  float e  = __expf(-2.f*xc);
  return (1.f - e) / (1.f + e);
}
#define MFMA16(a,b,c) __builtin_amdgcn_mfma_f32_16x16x32_f16((a),(b),(c),0,0,0)

// Z layout [k>>3][quad-implied][n][k&7]: flat idx = (k>>3)*(BT*8) + n*8 + (k&7)
__device__ __forceinline__ void zstS(_Float16* Z, int k, int n, _Float16 v){
  Z[(k >> 3)*(BT*8) + n*8 + (k & 7)] = v;
}

// Fused dual-stream: blocks [0,128)=CNN (fp16 x1), [128,256)=VQ (fp16 x2:
// weights single fp16, z split hi/lo fp16). 1024 thr = 16 waves.
// Wave w owns gate-row tile w with PERMUTED rows: tile row m <-> orig row
// 64*(m&3) + 4*w + (m>>2), so D-frag reg r = gate r of unit u=4w+quad,
// batch n16 -> LSTM act fully in-register. 2 barriers/step.
__global__ __launch_bounds__(1024)
__attribute__((amdgpu_waves_per_eu(4, 4)))
void fused_kernel(const float* __restrict__ xg,
                  const float* __restrict__ conv_w, const float* __restrict__ conv_b,
                  const float* __restrict__ bn_g, const float* __restrict__ bn_b,
                  const float* __restrict__ bn_m, const float* __restrict__ bn_v,
                  const float* __restrict__ cnn0_wih, const float* __restrict__ cnn0_whh,
                  const float* __restrict__ cnn0_bih, const float* __restrict__ cnn0_bhh,
                  const float* __restrict__ cnn1_wih, const float* __restrict__ cnn1_whh,
                  const float* __restrict__ cnn1_bih, const float* __restrict__ cnn1_bhh,
                  const float* __restrict__ vq0_wih, const float* __restrict__ vq0_whh,
                  const float* __restrict__ vq0_bih, const float* __restrict__ vq0_bhh,
                  const float* __restrict__ vq1_wih, const float* __restrict__ vq1_whh,
                  const float* __restrict__ vq1_bih, const float* __restrict__ vq1_bhh,
                  const float* __restrict__ proj_w, const float* __restrict__ proj_b,
                  const float* __restrict__ codebook,
                  float* __restrict__ out, float* __restrict__ ws_f,
                  int* __restrict__ ws_hist)
{
  __shared__ __align__(16) _Float16 Z0h[3][4][BT][8], Z0l[3][4][BT][8];  // K=96
  __shared__ __align__(16) _Float16 Z1h[4][4][BT][8], Z1l[4][4][BT][8];  // K=128
  __shared__ __align__(16) float hfin[BT][HID];
  __shared__ __align__(16) float pbuf[BT][EDIM];
  __shared__ float wcs[16][32];
  __shared__ float xwin[3][BT][DIN];

  const int tid  = threadIdx.x;
  const bool is_cnn = (blockIdx.x < NBLK_STREAM);
  const int b0   = (is_cnn ? blockIdx.x : blockIdx.x - NBLK_STREAM) * BT;
  const int w    = tid >> 6;      // wave = M-tile
  const int lane = tid & 63;
  const int n16  = lane & 15;     // batch (B/D col)
  const int quad = lane >> 4;
  const int u    = 4*w + quad;    // unit owned by this lane

  const float* wih0 = is_cnn ? cnn0_wih : vq0_wih;
  const float* whh0 = is_cnn ? cnn0_whh : vq0_whh;
  const float* bih0 = is_cnn ? cnn0_bih : vq0_bih;
  const float* bhh0 = is_cnn ? cnn0_bhh : vq0_bhh;
  const float* wih1 = is_cnn ? cnn1_wih : vq1_wih;
  const float* whh1 = is_cnn ? cnn1_whh : vq1_whh;
  const float* bih1 = is_cnn ? cnn1_bih : vq1_bih;
  const float* bhh1 = is_cnn ? cnn1_bhh : vq1_bhh;

  // ---- A-frags fp16 single, permuted rows. A[m=lane&15][k=quad*8+j]
  const int orow = 64*(n16 & 3) + 4*w + (n16 >> 2);
  half8 Ah0[3], Ah1[4];
#pragma unroll
  for (int kt = 0; kt < 3; ++kt) {
    half8 vh;
#pragma unroll
    for (int j = 0; j < 8; ++j) {
      const int g = kt*32 + quad*8 + j;
      float wv;
      if (is_cnn) wv = (g < 32) ? wih0[orow*32 + g] : whh0[orow*64 + (g-32)];
      else        wv = (g < 5) ? wih0[orow*5 + g] : (g < 32 ? 0.f : whh0[orow*64 + (g-32)]);
      vh[j] = (_Float16)wv;
    }
    Ah0[kt] = vh;
  }
#pragma unroll
  for (int kt = 0; kt < 4; ++kt) {
    half8 vh;
#pragma unroll
    for (int j = 0; j < 8; ++j) {
      const int g = kt*32 + quad*8 + j;
      float wv = (g < 64) ? wih1[orow*64 + g] : whh1[orow*64 + (g-64)];
      vh[j] = (_Float16)wv;
    }
    Ah1[kt] = vh;
  }

  // biases: gate r of unit u
  float bb0[4], bb1[4];
#pragma unroll
  for (int r = 0; r < 4; ++r) {
    bb0[r] = bih0[64*r + u] + bhh0[64*r + u];
    bb1[r] = bih1[64*r + u] + bhh1[64*r + u];
  }

  // zero Z operands (pads stay zero; h(-1)=0)
  for (int i2 = tid; i2 < 3*4*BT*8/2; i2 += 1024) { ((uint32_t*)Z0h)[i2] = 0; ((uint32_t*)Z0l)[i2] = 0; }
  for (int i2 = tid; i2 < 4*4*BT*8/2; i2 += 1024) { ((uint32_t*)Z1h)[i2] = 0; ((uint32_t*)Z1l)[i2] = 0; }

  const int xn = tid / 5, xi = tid % 5;
  float xpref = 0.f;

  // ================= prologue =================
  if (is_cnn) {
    if (tid < 32) {
      float s = bn_g[tid] * rsqrtf(bn_v[tid] + 1e-5f);
#pragma unroll
      for (int i = 0; i < 5; ++i)
#pragma unroll
        for (int tau = 0; tau < 3; ++tau)
          wcs[tau*5 + i][tid] = conv_w[tid*15 + i*3 + tau] * s;
      wcs[15][tid] = (conv_b[tid] - bn_m[tid]) * s + bn_b[tid];
    }
    if (tid < 80) {
      xwin[0][xn][xi] = xg[((size_t)(b0+xn)*SEQ + 0)*DIN + xi];
      xwin[1][xn][xi] = xg[((size_t)(b0+xn)*SEQ + 1)*DIN + xi];
      xwin[2][xn][xi] = xg[((size_t)(b0+xn)*SEQ + 2)*DIN + xi];
    }
    __syncthreads();
    if (tid < 512) {   // conv y(0): taps x(-1)=0, x(0), x(1)
      const int cc = tid >> 4, cn = tid & 15;
      float s = wcs[15][cc];
#pragma unroll
      for (int i = 0; i < 5; ++i)
        s += wcs[5+i][cc]*xwin[0][cn][i] + wcs[10+i][cc]*xwin[1][cn][i];
      s = fmaxf(s, 0.f);
      zstS((_Float16*)Z0h, cc, cn, (_Float16)s);
    }
  } else {
    if (tid < 80) {   // x(0) into Z0 k<5, hi/lo
      float xv = xg[((size_t)(b0+xn)*SEQ + 0)*DIN + xi];
      _Float16 hh = (_Float16)xv;
      zstS((_Float16*)Z0h, xi, xn, hh);
      zstS((_Float16*)Z0l, xi, xn, (_Float16)(xv - (float)hh));
    }
  }
  __syncthreads();

  float c0 = 0.f, c1 = 0.f, h1v = 0.f;
  // MFMA G0(0)
  {
    float4v A0 = {0,0,0,0};
#pragma unroll
    for (int kt = 0; kt < 3; ++kt) {
      half8 bh = *(const half8*)&Z0h[kt][quad][n16][0];
      A0 = MFMA16(Ah0[kt], bh, A0);
      if (!is_cnn) {
        half8 bl = *(const half8*)&Z0l[kt][quad][n16][0];
        A0 = MFMA16(Ah0[kt], bl, A0);
      }
    }
    __syncthreads();   // reads done before act writes
    float gi = A0[0]+bb0[0], gf = A0[1]+bb0[1], gg = A0[2]+bb0[2], go = A0[3]+bb0[3];
    c0 = fsig(gf)*c0 + fsig(gi)*ftanh(gg);
    float h0 = fsig(go)*ftanh(c0);
    _Float16 hh = (_Float16)h0;
    zstS((_Float16*)Z1h, u,      n16, hh);
    zstS((_Float16*)Z0h, 32 + u, n16, hh);
    if (!is_cnn) {
      _Float16 hl = (_Float16)(h0 - (float)hh);
      zstS((_Float16*)Z1l, u,      n16, hl);
      zstS((_Float16*)Z0l, 32 + u, n16, hl);
    }
  }
  // stage y(1)/x(1), prefetch
  if (is_cnn) {
    if (tid < 512) {   // conv y(1): x(0),x(1),x(2)
      const int cc = tid >> 4, cn = tid & 15;
      float s = wcs[15][cc];
#pragma unroll
      for (int i = 0; i < 5; ++i)
        s += wcs[i][cc]*xwin[0][cn][i] + wcs[5+i][cc]*xwin[1][cn][i]
           + wcs[10+i][cc]*xwin[2][cn][i];
      s = fmaxf(s, 0.f);
      zstS((_Float16*)Z0h, cc, cn, (_Float16)s);
    }
    if (tid < 80) xpref = xg[((size_t)(b0+xn)*SEQ + 3)*DIN + xi];   // x(3)
  } else {
    if (tid < 80) {    // x(1) into Z0 k<5
      float xv = xg[((size_t)(b0+xn)*SEQ + 1)*DIN + xi];
      _Float16 hh = (_Float16)xv;
      zstS((_Float16*)Z0h, xi, xn, hh);
      zstS((_Float16*)Z0l, xi, xn, (_Float16)(xv - (float)hh));
      xpref = xg[((size_t)(b0+xn)*SEQ + 2)*DIN + xi];               // x(2)
    }
  }
  __syncthreads();

  int sp = 1, scu = 2, snx = 0;   // cnn xwin slots: x(t+1), x(t+2), x(t+3)-incoming

  // ================= main loop: 2 barriers/step =================
  for (int t = 0; t < SEQ; ++t) {
    // ---- phase A: commit x(t+3) (cnn) + MFMA G1(t), G0(t+1)
    if (is_cnn && tid < 80) xwin[snx][xn][xi] = xpref;
    float4v A1 = {0,0,0,0}, A0 = {0,0,0,0};
    if (is_cnn) {
#pragma unroll
      for (int kt = 0; kt < 4; ++kt) {
        half8 bh = *(const half8*)&Z1h[kt][quad][n16][0];
        A1 = MFMA16(Ah1[kt], bh, A1);
      }
#pragma unroll
      for (int kt = 0; kt < 3; ++kt) {
        half8 bh = *(const half8*)&Z0h[kt][quad][n16][0];
        A0 = MFMA16(Ah0[kt], bh, A0);
      }
    } else {
#pragma unroll
      for (int kt = 0; kt < 4; ++kt) {
        half8 bh = *(const half8*)&Z1h[kt][quad][n16][0];
        half8 bl = *(const half8*)&Z1l[kt][quad][n16][0];
        A1 = MFMA16(Ah1[kt], bh, A1);
        A1 = MFMA16(Ah1[kt], bl, A1);
      }
#pragma unroll
      for (int kt = 0; kt < 3; ++kt) {
        half8 bh = *(const half8*)&Z0h[kt][quad][n16][0];
        half8 bl = *(const half8*)&Z0l[kt][quad][n16][0];
        A0 = MFMA16(Ah0[kt], bh, A0);
        A0 = MFMA16(Ah0[kt], bl, A0);
      }
    }
    __syncthreads();  // A -> B (Z reads complete)

    // ---- phase B: in-register acts + Z writes + conv/x staging
    {  // L1 act(t)
      float gi = A1[0]+bb1[0], gf = A1[1]+bb1[1], gg = A1[2]+bb1[2], go = A1[3]+bb1[3];
      c1 = fsig(gf)*c1 + fsig(gi)*ftanh(gg);
      float h1 = fsig(go)*ftanh(c1);
      _Float16 hh = (_Float16)h1;
      zstS((_Float16*)Z1h, 64 + u, n16, hh);
      if (!is_cnn) {
        zstS((_Float16*)Z1l, 64 + u, n16, (_Float16)(h1 - (float)hh));
        if (t == SEQ-1) hfin[n16][u] = h1;
      } else h1v = h1;
    }
    {  // L0 act(t+1)
      float gi = A0[0]+bb0[0], gf = A0[1]+bb0[1], gg = A0[2]+bb0[2], go = A0[3]+bb0[3];
      c0 = fsig(gf)*c0 + fsig(gi)*ftanh(gg);
      float h0 = fsig(go)*ftanh(c0);
      _Float16 hh = (_Float16)h0;
      zstS((_Float16*)Z1h, u,      n16, hh);
      zstS((_Float16*)Z0h, 32 + u, n16, hh);
      if (!is_cnn) {
        _Float16 hl = (_Float16)(h0 - (float)hh);
        zstS((_Float16*)Z1l, u,      n16, hl);
        zstS((_Float16*)Z0l, 32 + u, n16, hl);
      }
    }
    if (is_cnn) {      // conv y(t+2): x(t+1),x(t+2),x(t+3)
      if (tid < 512) {
        const int cc = tid >> 4, cn = tid & 15;
        float s = wcs[15][cc];
#pragma unroll
        for (int i = 0; i < 5; ++i)
          s += wcs[i][cc]*xwin[sp][cn][i] + wcs[5+i][cc]*xwin[scu][cn][i]
             + wcs[10+i][cc]*xwin[snx][cn][i];
        s = fmaxf(s, 0.f);
        zstS((_Float16*)Z0h, cc, cn, (_Float16)s);
      }
      if (tid < 80) {
        const int tq = t + 4;
        xpref = (tq < SEQ) ? xg[((size_t)(b0+xn)*SEQ + tq)*DIN + xi] : 0.f;
      }
    } else {
      if (tid < 80) {  // x(t+2) into Z0 k<5
        _Float16 hh = (_Float16)xpref;
        zstS((_Float16*)Z0h, xi, xn, hh);
        zstS((_Float16*)Z0l, xi, xn, (_Float16)(xpref - (float)hh));
        const int tq = t + 3;
        xpref = (tq < SEQ) ? xg[((size_t)(b0+xn)*SEQ + tq)*DIN + xi] : 0.f;
      }
    }
    { int tmp = sp; sp = scu; scu = snx; snx = tmp; }
    __syncthreads();  // B -> A(t+1)
  }

  // ================= epilogue =================
  if (is_cnn) {
    const size_t gb = (size_t)(b0 + n16);
    out[gb*COMB + u]        = h1v;
    out[OUTC + gb*COMB + u] = h1v;
  } else {
    if (tid < 512) {  // projection: vq_proj[16][32]
      const int pn = tid >> 5, pe = tid & 31;
      float s = proj_b[pe];
      const float* pw = proj_w + pe*HID;
#pragma unroll
      for (int k = 0; k < HID; ++k) s += hfin[pn][k] * pw[k];
      pbuf[pn][pe] = s;
    }
    __syncthreads();
    // argmin: wave w handles batch w, lane = code idx
    {
      const int bb = w;
      const int nn = lane;
      const float* cbn = codebook + nn*EDIM;
      float d = 0.f;
#pragma unroll
      for (int k = 0; k < EDIM; ++k) { float df = pbuf[bb][k] - cbn[k]; d += df*df; }
      int bi = nn;
#pragma unroll
      for (int off = 32; off > 0; off >>= 1) {
        float od = __shfl_down(d, off, 64);
        int   oi = __shfl_down(bi, off, 64);
        if (od < d || (od == d && oi < bi)) { d = od; bi = oi; }
      }
      bi = __shfl(bi, 0, 64);
      float lv = 0.f;
      if (nn < EDIM) {
        float q = codebook[bi*EDIM + nn];
        const size_t gb = (size_t)(b0 + bb);
        out[gb*COMB + HID + nn]        = q;
        out[OUTC + gb*COMB + HID + nn] = q;
        float df = q - pbuf[bb][nn];
        lv = df*df;
      }
#pragma unroll
      for (int off = 32; off > 0; off >>= 1) lv += __shfl_down(lv, off, 64);
      if (nn == 0) { atomicAdd(ws_f, lv); atomicAdd(&ws_hist[bi], 1); }
    }
  }
}

// ===================== scalars =====================
__global__ void zero_ws_kernel(float* ws_f, int* ws_hist) {
  const int t = threadIdx.x;
  if (t == 0) ws_f[0] = 0.f;
  if (t < NEMB) ws_hist[t] = 0;
}

__global__ void vq_finalize_kernel(const float* __restrict__ ws_f,
                                   const int* __restrict__ ws_hist,
                                   float* __restrict__ out) {
  const int t = threadIdx.x;  // 64 threads = 1 wave
  float p = (float)ws_hist[t] * (1.0f / (float)B_TOT);
  float e = -p * logf(p + 1e-10f);
#pragma unroll
  for (int off = 32; off > 0; off >>= 1) e += __shfl_down(e, off, 64);
  if (t == 0) {
    float mse = ws_f[0] * (1.0f / (float)(B_TOT * EDIM));
    out[2*OUTC + 0] = mse * 1.01f;   // q_loss + 0.01*e_loss (identical fwd)
    out[2*OUTC + 1] = expf(e);       // perplexity
  }
}

extern "C" void kernel_launch(void* const* d_in, const int* in_sizes, int n_in,
                              void* d_out, int out_size, void* d_ws, size_t ws_size,
                              hipStream_t stream) {
  const float* x        = (const float*)d_in[0];
  const float* conv_w   = (const float*)d_in[1];
  const float* conv_b   = (const float*)d_in[2];
  const float* bn_g     = (const float*)d_in[3];
  const float* bn_b     = (const float*)d_in[4];
  const float* bn_m     = (const float*)d_in[5];
  const float* bn_v     = (const float*)d_in[6];
  const float* cnn0_wih = (const float*)d_in[7];
  const float* cnn0_whh = (const float*)d_in[8];
  const float* cnn0_bih = (const float*)d_in[9];
  const float* cnn0_bhh = (const float*)d_in[10];
  const float* cnn1_wih = (const float*)d_in[11];
  const float* cnn1_whh = (const float*)d_in[12];
  const float* cnn1_bih = (const float*)d_in[13];
  const float* cnn1_bhh = (const float*)d_in[14];
  const float* vq0_wih  = (const float*)d_in[15];
  const float* vq0_whh  = (const float*)d_in[16];
  const float* vq0_bih  = (const float*)d_in[17];
  const float* vq0_bhh  = (const float*)d_in[18];
  const float* vq1_wih  = (const float*)d_in[19];
  const float* vq1_whh  = (const float*)d_in[20];
  const float* vq1_bih  = (const float*)d_in[21];
  const float* vq1_bhh  = (const float*)d_in[22];
  const float* proj_w   = (const float*)d_in[23];
  const float* proj_b   = (const float*)d_in[24];
  const float* codebook = (const float*)d_in[25];

  float* out     = (float*)d_out;
  float* ws_f    = (float*)d_ws;
  int*   ws_hist = (int*)d_ws + 16;

  hipLaunchKernelGGL(zero_ws_kernel, dim3(1), dim3(64), 0, stream, ws_f, ws_hist);
  hipLaunchKernelGGL(fused_kernel, dim3(2*NBLK_STREAM), dim3(1024), 0, stream,
                     x, conv_w, conv_b, bn_g, bn_b, bn_m, bn_v,
                     cnn0_wih, cnn0_whh, cnn0_bih, cnn0_bhh,
                     cnn1_wih, cnn1_whh, cnn1_bih, cnn1_bhh,
                     vq0_wih, vq0_whh, vq0_bih, vq0_bhh,
                     vq1_wih, vq1_whh, vq1_bih, vq1_bhh,
                     proj_w, proj_b, codebook, out, ws_f, ws_hist);
  hipLaunchKernelGGL(vq_finalize_kernel, dim3(1), dim3(64), 0, stream, ws_f, ws_hist, out);
}

// Round 8
// 1004.144 us; speedup vs baseline: 5.8075x; 1.0586x over previous
//
#include <hip/hip_runtime.h>
#include <math.h>
#include <stdint.h>

#define B_TOT 2048
#define SEQ   512
#define DIN   5
#define HID   64
#define EDIM  32
#define NEMB  64
#define BT    16
#define NBLK_STREAM 128
#define COMB  96
#define OUTC  (B_TOT*COMB)

typedef __attribute__((ext_vector_type(8))) _Float16 half8;  // 8 fp16 = 4 VGPRs
typedef __attribute__((ext_vector_type(4))) float float4v;

__device__ __forceinline__ float fsig(float x){ return 1.0f/(1.0f + __expf(-x)); }
__device__ __forceinline__ float ftanh(float x){
  float xc = fminf(fmaxf(x, -15.f), 15.f);
  float e  = __expf(-2.f*xc);
  return (1.f - e) / (1.f + e);
}
#define MFMA16(a,b,c) __builtin_amdgcn_mfma_f32_16x16x32_f16((a),(b),(c),0,0,0)

// Z layout: flat halfword idx = (k>>3)*(BT*8) + n*8 + (k&7)
__device__ __forceinline__ void zstS(_Float16* Z, int k, int n, _Float16 v){
  Z[(k >> 3)*(BT*8) + n*8 + (k & 7)] = v;
}

// Fused dual-stream, single-fp16 both streams. blocks [0,128)=CNN, [128,256)=VQ.
// 1024 thr = 16 waves. Wave w owns gate-row tile w with PERMUTED rows:
// tile row m <-> orig row 64*(m&3) + 4*w + (m>>2), so D-frag reg r = gate r of
// unit u=4w+quad, batch n16 -> LSTM act fully in-register. 2 barriers/step.
__global__ __launch_bounds__(1024)
__attribute__((amdgpu_waves_per_eu(4, 4)))
void fused_kernel(const float* __restrict__ xg,
                  const float* __restrict__ conv_w, const float* __restrict__ conv_b,
                  const float* __restrict__ bn_g, const float* __restrict__ bn_b,
                  const float* __restrict__ bn_m, const float* __restrict__ bn_v,
                  const float* __restrict__ cnn0_wih, const float* __restrict__ cnn0_whh,
                  const float* __restrict__ cnn0_bih, const float* __restrict__ cnn0_bhh,
                  const float* __restrict__ cnn1_wih, const float* __restrict__ cnn1_whh,
                  const float* __restrict__ cnn1_bih, const float* __restrict__ cnn1_bhh,
                  const float* __restrict__ vq0_wih, const float* __restrict__ vq0_whh,
                  const float* __restrict__ vq0_bih, const float* __restrict__ vq0_bhh,
                  const float* __restrict__ vq1_wih, const float* __restrict__ vq1_whh,
                  const float* __restrict__ vq1_bih, const float* __restrict__ vq1_bhh,
                  const float* __restrict__ proj_w, const float* __restrict__ proj_b,
                  const float* __restrict__ codebook,
                  float* __restrict__ out, float* __restrict__ ws_f,
                  int* __restrict__ ws_hist)
{
  __shared__ __align__(16) _Float16 Z0h[3][4][BT][8];   // K=96 operand
  __shared__ __align__(16) _Float16 Z1h[4][4][BT][8];   // K=128 operand
  __shared__ __align__(16) float hfin[BT][HID];
  __shared__ __align__(16) float pbuf[BT][EDIM];
  __shared__ float wcs[16][32];
  __shared__ float xwin[3][BT][DIN];

  const int tid  = threadIdx.x;
  const bool is_cnn = (blockIdx.x < NBLK_STREAM);
  const int b0   = (is_cnn ? blockIdx.x : blockIdx.x - NBLK_STREAM) * BT;
  const int w    = tid >> 6;      // wave = M-tile
  const int lane = tid & 63;
  const int n16  = lane & 15;     // batch (B/D col)
  const int quad = lane >> 4;
  const int u    = 4*w + quad;    // unit owned by this lane

  const float* wih0 = is_cnn ? cnn0_wih : vq0_wih;
  const float* whh0 = is_cnn ? cnn0_whh : vq0_whh;
  const float* bih0 = is_cnn ? cnn0_bih : vq0_bih;
  const float* bhh0 = is_cnn ? cnn0_bhh : vq0_bhh;
  const float* wih1 = is_cnn ? cnn1_wih : vq1_wih;
  const float* whh1 = is_cnn ? cnn1_whh : vq1_whh;
  const float* bih1 = is_cnn ? cnn1_bih : vq1_bih;
  const float* bhh1 = is_cnn ? cnn1_bhh : vq1_bhh;

  // ---- A-frags fp16, permuted rows. A[m=lane&15][k=quad*8+j]
  const int orow = 64*(n16 & 3) + 4*w + (n16 >> 2);
  half8 Ah0[3], Ah1[4];
#pragma unroll
  for (int kt = 0; kt < 3; ++kt) {
    half8 vh;
#pragma unroll
    for (int j = 0; j < 8; ++j) {
      const int g = kt*32 + quad*8 + j;
      float wv;
      if (is_cnn) wv = (g < 32) ? wih0[orow*32 + g] : whh0[orow*64 + (g-32)];
      else        wv = (g < 5) ? wih0[orow*5 + g] : (g < 32 ? 0.f : whh0[orow*64 + (g-32)]);
      vh[j] = (_Float16)wv;
    }
    Ah0[kt] = vh;
  }
#pragma unroll
  for (int kt = 0; kt < 4; ++kt) {
    half8 vh;
#pragma unroll
    for (int j = 0; j < 8; ++j) {
      const int g = kt*32 + quad*8 + j;
      float wv = (g < 64) ? wih1[orow*64 + g] : whh1[orow*64 + (g-64)];
      vh[j] = (_Float16)wv;
    }
    Ah1[kt] = vh;
  }

  // biases: gate r of unit u
  float bb0[4], bb1[4];
#pragma unroll
  for (int r = 0; r < 4; ++r) {
    bb0[r] = bih0[64*r + u] + bhh0[64*r + u];
    bb1[r] = bih1[64*r + u] + bhh1[64*r + u];
  }

  // zero Z operands (pads stay zero; h(-1)=0)
  for (int i2 = tid; i2 < 3*4*BT*8/2; i2 += 1024) ((uint32_t*)Z0h)[i2] = 0;
  for (int i2 = tid; i2 < 4*4*BT*8/2; i2 += 1024) ((uint32_t*)Z1h)[i2] = 0;

  const int xn = tid / 5, xi = tid % 5;
  float xpref = 0.f;

  // ================= prologue =================
  if (is_cnn) {
    if (tid < 32) {
      float s = bn_g[tid] * rsqrtf(bn_v[tid] + 1e-5f);
#pragma unroll
      for (int i = 0; i < 5; ++i)
#pragma unroll
        for (int tau = 0; tau < 3; ++tau)
          wcs[tau*5 + i][tid] = conv_w[tid*15 + i*3 + tau] * s;
      wcs[15][tid] = (conv_b[tid] - bn_m[tid]) * s + bn_b[tid];
    }
    if (tid < 80) {
      xwin[0][xn][xi] = xg[((size_t)(b0+xn)*SEQ + 0)*DIN + xi];
      xwin[1][xn][xi] = xg[((size_t)(b0+xn)*SEQ + 1)*DIN + xi];
      xwin[2][xn][xi] = xg[((size_t)(b0+xn)*SEQ + 2)*DIN + xi];
    }
    __syncthreads();
    if (tid < 512) {   // conv y(0): taps x(-1)=0, x(0), x(1)
      const int cc = tid >> 4, cn = tid & 15;
      float s = wcs[15][cc];
#pragma unroll
      for (int i = 0; i < 5; ++i)
        s += wcs[5+i][cc]*xwin[0][cn][i] + wcs[10+i][cc]*xwin[1][cn][i];
      s = fmaxf(s, 0.f);
      zstS((_Float16*)Z0h, cc, cn, (_Float16)s);
    }
  } else {
    if (tid < 80) {   // x(0) into Z0 k<5
      float xv = xg[((size_t)(b0+xn)*SEQ + 0)*DIN + xi];
      zstS((_Float16*)Z0h, xi, xn, (_Float16)xv);
    }
  }
  __syncthreads();

  float c0 = 0.f, c1 = 0.f, h1v = 0.f;
  // MFMA G0(0)
  {
    float4v A0 = {0,0,0,0};
#pragma unroll
    for (int kt = 0; kt < 3; ++kt) {
      half8 bh = *(const half8*)&Z0h[kt][quad][n16][0];
      A0 = MFMA16(Ah0[kt], bh, A0);
    }
    __syncthreads();   // reads done before act writes
    float gi = A0[0]+bb0[0], gf = A0[1]+bb0[1], gg = A0[2]+bb0[2], go = A0[3]+bb0[3];
    c0 = fsig(gf)*c0 + fsig(gi)*ftanh(gg);
    float h0 = fsig(go)*ftanh(c0);
    _Float16 hh = (_Float16)h0;
    zstS((_Float16*)Z1h, u,      n16, hh);
    zstS((_Float16*)Z0h, 32 + u, n16, hh);
  }
  // stage y(1)/x(1), prefetch
  if (is_cnn) {
    if (tid < 512) {   // conv y(1): x(0),x(1),x(2)
      const int cc = tid >> 4, cn = tid & 15;
      float s = wcs[15][cc];
#pragma unroll
      for (int i = 0; i < 5; ++i)
        s += wcs[i][cc]*xwin[0][cn][i] + wcs[5+i][cc]*xwin[1][cn][i]
           + wcs[10+i][cc]*xwin[2][cn][i];
      s = fmaxf(s, 0.f);
      zstS((_Float16*)Z0h, cc, cn, (_Float16)s);
    }
    if (tid < 80) xpref = xg[((size_t)(b0+xn)*SEQ + 3)*DIN + xi];   // x(3)
  } else {
    if (tid < 80) {    // x(1) into Z0 k<5
      float xv = xg[((size_t)(b0+xn)*SEQ + 1)*DIN + xi];
      zstS((_Float16*)Z0h, xi, xn, (_Float16)xv);
      xpref = xg[((size_t)(b0+xn)*SEQ + 2)*DIN + xi];               // x(2)
    }
  }
  __syncthreads();

  int sp = 1, scu = 2, snx = 0;   // cnn xwin slots: x(t+1), x(t+2), x(t+3)-incoming

  // ================= main loop: 2 barriers/step =================
  for (int t = 0; t < SEQ; ++t) {
    // ---- phase A: commit x(t+3) (cnn) + MFMA G1(t), G0(t+1)
    if (is_cnn && tid < 80) xwin[snx][xn][xi] = xpref;
    float4v A1 = {0,0,0,0}, A0 = {0,0,0,0};
#pragma unroll
    for (int kt = 0; kt < 4; ++kt) {
      half8 bh = *(const half8*)&Z1h[kt][quad][n16][0];
      A1 = MFMA16(Ah1[kt], bh, A1);
    }
#pragma unroll
    for (int kt = 0; kt < 3; ++kt) {
      half8 bh = *(const half8*)&Z0h[kt][quad][n16][0];
      A0 = MFMA16(Ah0[kt], bh, A0);
    }
    __syncthreads();  // A -> B (Z reads complete)

    // ---- phase B: in-register acts + Z writes + conv/x staging
    {  // L1 act(t)
      float gi = A1[0]+bb1[0], gf = A1[1]+bb1[1], gg = A1[2]+bb1[2], go = A1[3]+bb1[3];
      c1 = fsig(gf)*c1 + fsig(gi)*ftanh(gg);
      float h1 = fsig(go)*ftanh(c1);
      zstS((_Float16*)Z1h, 64 + u, n16, (_Float16)h1);
      if (is_cnn) h1v = h1;
      else if (t == SEQ-1) hfin[n16][u] = h1;
    }
    {  // L0 act(t+1)
      float gi = A0[0]+bb0[0], gf = A0[1]+bb0[1], gg = A0[2]+bb0[2], go = A0[3]+bb0[3];
      c0 = fsig(gf)*c0 + fsig(gi)*ftanh(gg);
      float h0 = fsig(go)*ftanh(c0);
      _Float16 hh = (_Float16)h0;
      zstS((_Float16*)Z1h, u,      n16, hh);
      zstS((_Float16*)Z0h, 32 + u, n16, hh);
    }
    if (is_cnn) {      // conv y(t+2): x(t+1),x(t+2),x(t+3)
      if (tid < 512) {
        const int cc = tid >> 4, cn = tid & 15;
        float s = wcs[15][cc];
#pragma unroll
        for (int i = 0; i < 5; ++i)
          s += wcs[i][cc]*xwin[sp][cn][i] + wcs[5+i][cc]*xwin[scu][cn][i]
             + wcs[10+i][cc]*xwin[snx][cn][i];
        s = fmaxf(s, 0.f);
        zstS((_Float16*)Z0h, cc, cn, (_Float16)s);
      }
      if (tid < 80) {
        const int tq = t + 4;
        xpref = (tq < SEQ) ? xg[((size_t)(b0+xn)*SEQ + tq)*DIN + xi] : 0.f;
      }
    } else {
      if (tid < 80) {  // x(t+2) into Z0 k<5
        zstS((_Float16*)Z0h, xi, xn, (_Float16)xpref);
        const int tq = t + 3;
        xpref = (tq < SEQ) ? xg[((size_t)(b0+xn)*SEQ + tq)*DIN + xi] : 0.f;
      }
    }
    { int tmp = sp; sp = scu; scu = snx; snx = tmp; }
    __syncthreads();  // B -> A(t+1)
  }

  // ================= epilogue =================
  if (is_cnn) {
    const size_t gb = (size_t)(b0 + n16);
    out[gb*COMB + u]        = h1v;
    out[OUTC + gb*COMB + u] = h1v;
  } else {
    if (tid < 512) {  // projection: vq_proj[16][32]
      const int pn = tid >> 5, pe = tid & 31;
      float s = proj_b[pe];
      const float* pw = proj_w + pe*HID;
#pragma unroll
      for (int k = 0; k < HID; ++k) s += hfin[pn][k] * pw[k];
      pbuf[pn][pe] = s;
    }
    __syncthreads();
    // argmin: wave w handles batch w, lane = code idx
    {
      const int bb = w;
      const int nn = lane;
      const float* cbn = codebook + nn*EDIM;
      float d = 0.f;
#pragma unroll
      for (int k = 0; k < EDIM; ++k) { float df = pbuf[bb][k] - cbn[k]; d += df*df; }
      int bi = nn;
#pragma unroll
      for (int off = 32; off > 0; off >>= 1) {
        float od = __shfl_down(d, off, 64);
        int   oi = __shfl_down(bi, off, 64);
        if (od < d || (od == d && oi < bi)) { d = od; bi = oi; }
      }
      bi = __shfl(bi, 0, 64);
      float lv = 0.f;
      if (nn < EDIM) {
        float q = codebook[bi*EDIM + nn];
        const size_t gb = (size_t)(b0 + bb);
        out[gb*COMB + HID + nn]        = q;
        out[OUTC + gb*COMB + HID + nn] = q;
        float df = q - pbuf[bb][nn];
        lv = df*df;
      }
#pragma unroll
      for (int off = 32; off > 0; off >>= 1) lv += __shfl_down(lv, off, 64);
      if (nn == 0) { atomicAdd(ws_f, lv); atomicAdd(&ws_hist[bi], 1); }
    }
  }
}

// ===================== scalars =====================
__global__ void zero_ws_kernel(float* ws_f, int* ws_hist) {
  const int t = threadIdx.x;
  if (t == 0) ws_f[0] = 0.f;
  if (t < NEMB) ws_hist[t] = 0;
}

__global__ void vq_finalize_kernel(const float* __restrict__ ws_f,
                                   const int* __restrict__ ws_hist,
                                   float* __restrict__ out) {
  const int t = threadIdx.x;  // 64 threads = 1 wave
  float p = (float)ws_hist[t] * (1.0f / (float)B_TOT);
  float e = -p * logf(p + 1e-10f);
#pragma unroll
  for (int off = 32; off > 0; off >>= 1) e += __shfl_down(e, off, 64);
  if (t == 0) {
    float mse = ws_f[0] * (1.0f / (float)(B_TOT * EDIM));
    out[2*OUTC + 0] = mse * 1.01f;   // q_loss + 0.01*e_loss (identical fwd)
    out[2*OUTC + 1] = expf(e);       // perplexity
  }
}

extern "C" void kernel_launch(void* const* d_in, const int* in_sizes, int n_in,
                              void* d_out, int out_size, void* d_ws, size_t ws_size,
                              hipStream_t stream) {
  const float* x        = (const float*)d_in[0];
  const float* conv_w   = (const float*)d_in[1];
  const float* conv_b   = (const float*)d_in[2];
  const float* bn_g     = (const float*)d_in[3];
  const float* bn_b     = (const float*)d_in[4];
  const float* bn_m     = (const float*)d_in[5];
  const float* bn_v     = (const float*)d_in[6];
  const float* cnn0_wih = (const float*)d_in[7];
  const float* cnn0_whh = (const float*)d_in[8];
  const float* cnn0_bih = (const float*)d_in[9];
  const float* cnn0_bhh = (const float*)d_in[10];
  const float* cnn1_wih = (const float*)d_in[11];
  const float* cnn1_whh = (const float*)d_in[12];
  const float* cnn1_bih = (const float*)d_in[13];
  const float* cnn1_bhh = (const float*)d_in[14];
  const float* vq0_wih  = (const float*)d_in[15];
  const float* vq0_whh  = (const float*)d_in[16];
  const float* vq0_bih  = (const float*)d_in[17];
  const float* vq0_bhh  = (const float*)d_in[18];
  const float* vq1_wih  = (const float*)d_in[19];
  const float* vq1_whh  = (const float*)d_in[20];
  const float* vq1_bih  = (const float*)d_in[21];
  const float* vq1_bhh  = (const float*)d_in[22];
  const float* proj_w   = (const float*)d_in[23];
  const float* proj_b   = (const float*)d_in[24];
  const float* codebook = (const float*)d_in[25];

  float* out     = (float*)d_out;
  float* ws_f    = (float*)d_ws;
  int*   ws_hist = (int*)d_ws + 16;

  hipLaunchKernelGGL(zero_ws_kernel, dim3(1), dim3(64), 0, stream, ws_f, ws_hist);
  hipLaunchKernelGGL(fused_kernel, dim3(2*NBLK_STREAM), dim3(1024), 0, stream,
                     x, conv_w, conv_b, bn_g, bn_b, bn_m, bn_v,
                     cnn0_wih, cnn0_whh, cnn0_bih, cnn0_bhh,
                     cnn1_wih, cnn1_whh, cnn1_bih, cnn1_bhh,
                     vq0_wih, vq0_whh, vq0_bih, vq0_bhh,
                     vq1_wih, vq1_whh, vq1_bih, vq1_bhh,
                     proj_w, proj_b, codebook, out, ws_f, ws_hist);
  hipLaunchKernelGGL(vq_finalize_kernel, dim3(1), dim3(64), 0, stream, ws_f, ws_hist, out);
}